// Round 1
// baseline (2957.244 us; speedup 1.0000x reference)
//
#include <hip/hip_runtime.h>

#define N_NODES    100000
#define N_DIH      1000000
#define SCALAR_DIM 128
#define HIDDEN     64
#define ATTR_DIM   3
#define D_IN       259          // 2*128 + 3

#define WAVES_PER_BLOCK 8
#define BLOCK (WAVES_PER_BLOCK * 64)
#define NGROUPS (N_DIH / 4)     // 250000, exact

__device__ __forceinline__ float silu(float v) {
    return v / (1.0f + __expf(-v));
}

__global__ void count_kernel(const int* __restrict__ qidx,
                             int* __restrict__ cnt_j, int* __restrict__ cnt_k) {
    int t = blockIdx.x * blockDim.x + threadIdx.x;
    if (t < N_DIH) {
        atomicAdd(&cnt_j[qidx[N_DIH + t]], 1);
        atomicAdd(&cnt_k[qidx[2 * N_DIH + t]], 1);
    }
}

__global__ void scale_kernel(const int* __restrict__ cnt_j, const int* __restrict__ cnt_k,
                             float* __restrict__ scale_j, float* __restrict__ scale_k) {
    int n = blockIdx.x * blockDim.x + threadIdx.x;
    if (n < N_NODES) {
        scale_j[n] = 0.5f / (float)max(cnt_j[n], 1);
        scale_k[n] = 0.5f / (float)max(cnt_k[n], 1);
    }
}

// Fused gather + 3-layer MLP + pre-scaled atomic scatter.
// One wave processes 4 dihedrals at a time; lane = hidden unit (64 lanes = 64 hiddens).
__global__ __launch_bounds__(BLOCK, 1) void mlp_kernel(
    const float* __restrict__ x, const int* __restrict__ qidx,
    const float* __restrict__ attr,
    const float* __restrict__ W1, const float* __restrict__ b1,
    const float* __restrict__ W2, const float* __restrict__ b2,
    const float* __restrict__ W3, const float* __restrict__ b3,
    const float* __restrict__ scale_j, const float* __restrict__ scale_k,
    float* __restrict__ aggr)
{
    __shared__ float W1s[D_IN * 64];                 // 66304 B, [d][c]
    __shared__ float W2s[64 * 64];                   // 16384 B, [d][c]
    __shared__ float W3s[64 * 128];                  // 32768 B, [d][o]
    __shared__ float b1s[64], b2s[64], b3s[128];
    __shared__ float in_t[WAVES_PER_BLOCK][260 * 4]; // transposed input [d][q], 33280 B
    __shared__ float h_buf[WAVES_PER_BLOCK][64 * 4]; // hidden [d][q], 8192 B
    // total static LDS ~158 KB <= 160 KB -> 1 block/CU, 8 waves/CU

    const int tid = threadIdx.x;
    for (int i = tid; i < D_IN * 64; i += BLOCK) W1s[i] = W1[i];
    for (int i = tid; i < 64 * 64; i += BLOCK)   W2s[i] = W2[i];
    for (int i = tid; i < 64 * 128; i += BLOCK)  W3s[i] = W3[i];
    if (tid < 64)  { b1s[tid] = b1[tid]; b2s[tid] = b2[tid]; }
    if (tid < 128) { b3s[tid] = b3[tid]; }
    __syncthreads();

    const int wave = tid >> 6;
    const int lane = tid & 63;
    float* my_in = in_t[wave];
    float* my_h  = h_buf[wave];

    const int groupStep = gridDim.x * WAVES_PER_BLOCK;
    for (int base = blockIdx.x * WAVES_PER_BLOCK; base < NGROUPS; base += groupStep) {
        const int g = base + wave;
        const bool active = (g < NGROUPS);

        __syncthreads();   // protect in_t from previous iteration's readers

        int jj[4], kk[4];
        if (active) {
            #pragma unroll
            for (int q = 0; q < 4; ++q) {
                const int t  = 4 * g + q;
                const int ii = qidx[t];
                const int ll = qidx[3 * N_DIH + t];
                jj[q] = qidx[N_DIH + t];
                kk[q] = qidx[2 * N_DIH + t];
                my_in[(lane)       * 4 + q] = x[ii * 128 + lane];
                my_in[(64 + lane)  * 4 + q] = x[ii * 128 + 64 + lane];
                my_in[(128 + lane) * 4 + q] = x[ll * 128 + lane];
                my_in[(192 + lane) * 4 + q] = x[ll * 128 + 64 + lane];
                if (lane < ATTR_DIM) my_in[(256 + lane) * 4 + q] = attr[t * 3 + lane];
            }
        }
        __syncthreads();

        if (active) {
            // ---- layer 1: 259 -> 64, lane computes hidden unit `lane` for 4 dihedrals
            float a0 = b1s[lane], a1 = a0, a2 = a0, a3 = a0;
            #pragma unroll 4
            for (int d = 0; d < D_IN; ++d) {
                const float4 iv = *(const float4*)&my_in[d * 4];
                const float w = W1s[d * 64 + lane];
                a0 += iv.x * w; a1 += iv.y * w; a2 += iv.z * w; a3 += iv.w * w;
            }
            float4 h;
            h.x = silu(a0); h.y = silu(a1); h.z = silu(a2); h.w = silu(a3);
            *(float4*)&my_h[lane * 4] = h;
        }
        __syncthreads();

        if (active) {
            // ---- layer 2: 64 -> 64
            float a0 = b2s[lane], a1 = a0, a2 = a0, a3 = a0;
            #pragma unroll 8
            for (int d = 0; d < 64; ++d) {
                const float4 hv = *(const float4*)&my_h[d * 4];
                const float w = W2s[d * 64 + lane];
                a0 += hv.x * w; a1 += hv.y * w; a2 += hv.z * w; a3 += hv.w * w;
            }
            float4 h;
            h.x = silu(a0); h.y = silu(a1); h.z = silu(a2); h.w = silu(a3);
            *(float4*)&my_in[lane * 4] = h;   // reuse in_t slab for h2
        }
        __syncthreads();

        if (active) {
            // ---- layer 3: 64 -> 128, lane computes out channels lane and lane+64
            float c00 = b3s[lane],      c01 = c00, c02 = c00, c03 = c00;
            float c10 = b3s[lane + 64], c11 = c10, c12 = c10, c13 = c10;
            #pragma unroll 8
            for (int d = 0; d < 64; ++d) {
                const float4 hv = *(const float4*)&my_in[d * 4];
                const float w0 = W3s[d * 128 + lane];
                const float w1 = W3s[d * 128 + 64 + lane];
                c00 += hv.x * w0; c01 += hv.y * w0; c02 += hv.z * w0; c03 += hv.w * w0;
                c10 += hv.x * w1; c11 += hv.y * w1; c12 += hv.z * w1; c13 += hv.w * w1;
            }
            const float m0[4] = {c00, c01, c02, c03};
            const float m1[4] = {c10, c11, c12, c13};
            #pragma unroll
            for (int q = 0; q < 4; ++q) {
                const float sj = scale_j[jj[q]];
                const float sk = scale_k[kk[q]];
                atomicAdd(&aggr[(size_t)jj[q] * 128 + lane],      m0[q] * sj);
                atomicAdd(&aggr[(size_t)jj[q] * 128 + 64 + lane], m1[q] * sj);
                atomicAdd(&aggr[(size_t)kk[q] * 128 + lane],      m0[q] * sk);
                atomicAdd(&aggr[(size_t)kk[q] * 128 + 64 + lane], m1[q] * sk);
            }
        }
    }
}

// out = aggr @ Wout ; wave-per-node, Wout in LDS, shuffle-broadcast of aggr row.
__global__ __launch_bounds__(256) void out_kernel(const float* __restrict__ aggr,
                                                  const float* __restrict__ Wout,
                                                  float* __restrict__ out) {
    __shared__ float Ws[128 * 128];   // 64 KB
    const int tid = threadIdx.x;
    for (int i = tid; i < 128 * 128; i += 256) Ws[i] = Wout[i];
    __syncthreads();

    const int wave = tid >> 6;
    const int lane = tid & 63;
    const int waveStep = gridDim.x * 4;
    for (int n = blockIdx.x * 4 + wave; n < N_NODES; n += waveStep) {
        const float a0 = aggr[(size_t)n * 128 + lane];
        const float a1 = aggr[(size_t)n * 128 + 64 + lane];
        float acc0 = 0.0f, acc1 = 0.0f;
        #pragma unroll
        for (int d = 0; d < 64; ++d) {
            const float s = __shfl(a0, d);
            acc0 += s * Ws[d * 128 + lane];
            acc1 += s * Ws[d * 128 + 64 + lane];
        }
        #pragma unroll
        for (int d = 0; d < 64; ++d) {
            const float s = __shfl(a1, d);
            acc0 += s * Ws[(64 + d) * 128 + lane];
            acc1 += s * Ws[(64 + d) * 128 + 64 + lane];
        }
        out[(size_t)n * 128 + lane] = acc0;
        out[(size_t)n * 128 + 64 + lane] = acc1;
    }
}

extern "C" void kernel_launch(void* const* d_in, const int* in_sizes, int n_in,
                              void* d_out, int out_size, void* d_ws, size_t ws_size,
                              hipStream_t stream) {
    const float* x    = (const float*)d_in[0];
    const int*   qidx = (const int*)d_in[1];
    const float* attr = (const float*)d_in[2];
    const float* W1   = (const float*)d_in[3];
    const float* b1   = (const float*)d_in[4];
    const float* W2   = (const float*)d_in[5];
    const float* b2   = (const float*)d_in[6];
    const float* W3   = (const float*)d_in[7];
    const float* b3   = (const float*)d_in[8];
    const float* Wout = (const float*)d_in[9];
    float* out = (float*)d_out;

    // ws layout: cnt_j[100k] int | cnt_k[100k] int | scale_j[100k] f32 | scale_k[100k] f32 | aggr[100k*128] f32
    int*   cnt_j   = (int*)d_ws;
    int*   cnt_k   = cnt_j + N_NODES;
    float* scale_j = (float*)(cnt_k + N_NODES);
    float* scale_k = scale_j + N_NODES;
    float* aggr    = scale_k + N_NODES;

    hipMemsetAsync(cnt_j, 0, (size_t)2 * N_NODES * sizeof(int), stream);
    hipMemsetAsync(aggr, 0, (size_t)N_NODES * 128 * sizeof(float), stream);

    count_kernel<<<(N_DIH + 255) / 256, 256, 0, stream>>>(qidx, cnt_j, cnt_k);
    scale_kernel<<<(N_NODES + 255) / 256, 256, 0, stream>>>(cnt_j, cnt_k, scale_j, scale_k);
    mlp_kernel<<<256, BLOCK, 0, stream>>>(x, qidx, attr, W1, b1, W2, b2, W3, b3,
                                          scale_j, scale_k, aggr);
    out_kernel<<<512, 256, 0, stream>>>(aggr, Wout, out);
}

// Round 2
// 2078.328 us; speedup vs baseline: 1.4229x; 1.4229x over previous
//
#include <hip/hip_runtime.h>

#define N_NODES    100000
#define N_DIH      1000000
#define SCALAR_DIM 128
#define HIDDEN     64
#define ATTR_DIM   3
#define D_IN       259

// ---------------- mlp kernel config ----------------
#define MB   512                 // 8 waves
#define TILE 64                  // dihedrals per block
#define NBATCH (N_DIH / TILE)    // 15625 exact

__device__ __forceinline__ float silu(float v) {
    return __fdividef(v, 1.0f + __expf(-v));
}

__global__ void count_kernel(const int* __restrict__ qidx,
                             int* __restrict__ cnt_j, int* __restrict__ cnt_k) {
    int t = blockIdx.x * blockDim.x + threadIdx.x;
    if (t < N_DIH) {
        atomicAdd(&cnt_j[qidx[N_DIH + t]], 1);
        atomicAdd(&cnt_k[qidx[2 * N_DIH + t]], 1);
    }
}

__global__ void scale_kernel(const int* __restrict__ cnt_j, const int* __restrict__ cnt_k,
                             float* __restrict__ scale_j, float* __restrict__ scale_k) {
    int n = blockIdx.x * blockDim.x + threadIdx.x;
    if (n < N_NODES) {
        scale_j[n] = 0.5f / (float)max(cnt_j[n], 1);
        scale_k[n] = 0.5f / (float)max(cnt_k[n], 1);
    }
}

// lane = dihedral (64/tile), wave = c-slice. Weights come in through the
// SCALAR pipe (wave-uniform indices -> s_load), inputs through one
// ds_read_b128 per 4 K-steps. LDS strides 260/68/132: start bank = 4*lane
// -> 2-way aliasing only (free).
__global__ __launch_bounds__(MB, 1) void mlp_kernel(
    const float* __restrict__ x, const int* __restrict__ qidx,
    const float* __restrict__ attr,
    const float* __restrict__ W1, const float* __restrict__ b1,
    const float* __restrict__ W2, const float* __restrict__ b2,
    const float* __restrict__ W3, const float* __restrict__ b3,
    const float* __restrict__ scale_j, const float* __restrict__ scale_k,
    float* __restrict__ aggr)
{
    __shared__ float in_lds[TILE * 260];   // 66560 B: [dih][0..255]=x_i|x_l, [256..258]=attr, [259]=0
    __shared__ float h_lds[TILE * 68];     // 17408 B
    __shared__ int   j_lds[TILE];
    __shared__ int   k_lds[TILE];
    __shared__ float sj_lds[TILE];
    __shared__ float sk_lds[TILE];
    float* msg_lds = in_lds;               // overlay [dih][132] once L1 reads are done (33792 B)

    const int tid  = threadIdx.x;
    const int lane = tid & 63;
    const int wv   = __builtin_amdgcn_readfirstlane(tid >> 6);  // 0..7, SGPR
    const int base = blockIdx.x * TILE;

    // ---------------- stage ----------------
    {
        const int half = lane >> 5;           // 0: x_i row, 1: x_l row
        const int q4   = (lane & 31) << 2;    // float4 offset within 128
        #pragma unroll
        for (int dd = 0; dd < 8; ++dd) {
            const int t  = wv * 8 + dd;               // uniform
            const int gi = qidx[base + t];            // s_load
            const int gl = qidx[3 * N_DIH + base + t];// s_load
            const int row = half ? gl : gi;
            const float4 v = *(const float4*)&x[(size_t)row * 128 + q4];
            *(float4*)&in_lds[t * 260 + half * 128 + q4] = v;
        }
        if (tid < 192) {
            const int dd = tid / 3, a = tid - dd * 3;
            in_lds[dd * 260 + 256 + a] = attr[(size_t)base * 3 + tid];
        } else if (tid < 256) {
            in_lds[(tid - 192) * 260 + 259] = 0.0f;
        } else if (tid < 320) {
            const int t  = tid - 256;
            const int jv = qidx[N_DIH + base + t];
            j_lds[t]  = jv;
            sj_lds[t] = scale_j[jv];
        } else if (tid < 384) {
            const int t  = tid - 320;
            const int kv = qidx[2 * N_DIH + base + t];
            k_lds[t]  = kv;
            sk_lds[t] = scale_k[kv];
        }
    }
    __syncthreads();

    const float* inp = &in_lds[lane * 260];
    const int c1 = wv * 8;     // L1/L2 c-slice: 8 channels per thread

    // ---------------- layer 1: 259 -> 64 ----------------
    float a1[8];
    #pragma unroll
    for (int c = 0; c < 8; ++c) a1[c] = b1[c1 + c];
    #pragma unroll 2
    for (int d = 0; d < 256; d += 4) {
        const float4 iv = *(const float4*)&inp[d];
        const float* w0 = &W1[(d + 0) * 64 + c1];
        const float* w1 = &W1[(d + 1) * 64 + c1];
        const float* w2 = &W1[(d + 2) * 64 + c1];
        const float* w3 = &W1[(d + 3) * 64 + c1];
        #pragma unroll
        for (int c = 0; c < 8; ++c)
            a1[c] += iv.x * w0[c] + iv.y * w1[c] + iv.z * w2[c] + iv.w * w3[c];
    }
    {   // tail: d = 256..258 (attr), in_lds[259] is zero-padded but W1 has no row 259
        const float4 iv = *(const float4*)&inp[256];
        const float* w0 = &W1[256 * 64 + c1];
        const float* w1 = &W1[257 * 64 + c1];
        const float* w2 = &W1[258 * 64 + c1];
        #pragma unroll
        for (int c = 0; c < 8; ++c)
            a1[c] += iv.x * w0[c] + iv.y * w1[c] + iv.z * w2[c];
    }
    #pragma unroll
    for (int c = 0; c < 8; ++c) a1[c] = silu(a1[c]);
    *(float4*)&h_lds[lane * 68 + c1]     = make_float4(a1[0], a1[1], a1[2], a1[3]);
    *(float4*)&h_lds[lane * 68 + c1 + 4] = make_float4(a1[4], a1[5], a1[6], a1[7]);
    __syncthreads();

    // ---------------- layer 2: 64 -> 64 ----------------
    const float* hp = &h_lds[lane * 68];
    float a2[8];
    #pragma unroll
    for (int c = 0; c < 8; ++c) a2[c] = b2[c1 + c];
    #pragma unroll 2
    for (int d = 0; d < 64; d += 4) {
        const float4 hv = *(const float4*)&hp[d];
        const float* w0 = &W2[(d + 0) * 64 + c1];
        const float* w1 = &W2[(d + 1) * 64 + c1];
        const float* w2 = &W2[(d + 2) * 64 + c1];
        const float* w3 = &W2[(d + 3) * 64 + c1];
        #pragma unroll
        for (int c = 0; c < 8; ++c)
            a2[c] += hv.x * w0[c] + hv.y * w1[c] + hv.z * w2[c] + hv.w * w3[c];
    }
    #pragma unroll
    for (int c = 0; c < 8; ++c) a2[c] = silu(a2[c]);
    __syncthreads();   // everyone done READING h1 before overwriting
    *(float4*)&h_lds[lane * 68 + c1]     = make_float4(a2[0], a2[1], a2[2], a2[3]);
    *(float4*)&h_lds[lane * 68 + c1 + 4] = make_float4(a2[4], a2[5], a2[6], a2[7]);
    __syncthreads();

    // ---------------- layer 3: 64 -> 128 ----------------
    const int c3 = wv * 16;    // 16 output channels per thread
    float a3[16];
    #pragma unroll
    for (int c = 0; c < 16; ++c) a3[c] = b3[c3 + c];
    #pragma unroll 2
    for (int d = 0; d < 64; d += 4) {
        const float4 hv = *(const float4*)&hp[d];
        const float* w0 = &W3[(d + 0) * 128 + c3];
        const float* w1 = &W3[(d + 1) * 128 + c3];
        const float* w2 = &W3[(d + 2) * 128 + c3];
        const float* w3r = &W3[(d + 3) * 128 + c3];
        #pragma unroll
        for (int c = 0; c < 16; ++c)
            a3[c] += hv.x * w0[c] + hv.y * w1[c] + hv.z * w2[c] + hv.w * w3r[c];
    }
    // msg -> LDS transpose (reuses in_lds; all in_lds reads finished before the h1 barrier)
    #pragma unroll
    for (int c = 0; c < 16; c += 4)
        *(float4*)&msg_lds[lane * 132 + c3 + c] = make_float4(a3[c], a3[c+1], a3[c+2], a3[c+3]);
    __syncthreads();

    // ---------------- coalesced pre-scaled atomic scatter ----------------
    #pragma unroll
    for (int dd = 0; dd < 8; ++dd) {
        const int t = wv * 8 + dd;                 // uniform
        const float v0 = msg_lds[t * 132 + lane];
        const float v1 = msg_lds[t * 132 + 64 + lane];
        const int   jv = j_lds[t];
        const int   kv = k_lds[t];
        const float sj = sj_lds[t];
        const float sk = sk_lds[t];
        atomicAdd(&aggr[(size_t)jv * 128 + lane],      v0 * sj);
        atomicAdd(&aggr[(size_t)jv * 128 + 64 + lane], v1 * sj);
        atomicAdd(&aggr[(size_t)kv * 128 + lane],      v0 * sk);
        atomicAdd(&aggr[(size_t)kv * 128 + 64 + lane], v1 * sk);
    }
}

// ---------------- out = aggr @ Wout ----------------
// Same structure: lane = node, wave = 32-channel slice, Wout via scalar loads.
#define OB    256
#define OTILE 64
__global__ __launch_bounds__(OB, 2) void out_kernel(const float* __restrict__ aggr,
                                                    const float* __restrict__ Wout,
                                                    float* __restrict__ out) {
    __shared__ float a_lds[OTILE * 132];   // 33792 B -> up to 4 blocks/CU
    const int tid  = threadIdx.x;
    const int lane = tid & 63;
    const int wv   = __builtin_amdgcn_readfirstlane(tid >> 6);  // 0..3
    const int base = blockIdx.x * OTILE;
    const int half = lane >> 5;
    const int q4   = (lane & 31) << 2;

    #pragma unroll
    for (int p = 0; p < 8; ++p) {
        const int ln = wv * 16 + p * 2 + half;
        const int n  = base + ln;
        float4 v = make_float4(0.f, 0.f, 0.f, 0.f);
        if (n < N_NODES) v = *(const float4*)&aggr[(size_t)n * 128 + q4];
        *(float4*)&a_lds[ln * 132 + q4] = v;
    }
    __syncthreads();

    const int c0 = wv * 32;
    float acc[32];
    #pragma unroll
    for (int c = 0; c < 32; ++c) acc[c] = 0.0f;
    const float* ap = &a_lds[lane * 132];
    #pragma unroll 2
    for (int d = 0; d < 128; d += 4) {
        const float4 av = *(const float4*)&ap[d];
        const float* w0 = &Wout[(d + 0) * 128 + c0];
        const float* w1 = &Wout[(d + 1) * 128 + c0];
        const float* w2 = &Wout[(d + 2) * 128 + c0];
        const float* w3 = &Wout[(d + 3) * 128 + c0];
        #pragma unroll
        for (int c = 0; c < 32; ++c)
            acc[c] += av.x * w0[c] + av.y * w1[c] + av.z * w2[c] + av.w * w3[c];
    }
    __syncthreads();   // a_lds reads done; reuse for output transpose
    #pragma unroll
    for (int c = 0; c < 32; c += 4)
        *(float4*)&a_lds[lane * 132 + c0 + c] = make_float4(acc[c], acc[c+1], acc[c+2], acc[c+3]);
    __syncthreads();
    #pragma unroll
    for (int p = 0; p < 8; ++p) {
        const int ln = wv * 16 + p * 2 + half;
        const int n  = base + ln;
        if (n < N_NODES)
            *(float4*)&out[(size_t)n * 128 + q4] = *(const float4*)&a_lds[ln * 132 + q4];
    }
}

extern "C" void kernel_launch(void* const* d_in, const int* in_sizes, int n_in,
                              void* d_out, int out_size, void* d_ws, size_t ws_size,
                              hipStream_t stream) {
    const float* x    = (const float*)d_in[0];
    const int*   qidx = (const int*)d_in[1];
    const float* attr = (const float*)d_in[2];
    const float* W1   = (const float*)d_in[3];
    const float* b1   = (const float*)d_in[4];
    const float* W2   = (const float*)d_in[5];
    const float* b2   = (const float*)d_in[6];
    const float* W3   = (const float*)d_in[7];
    const float* b3   = (const float*)d_in[8];
    const float* Wout = (const float*)d_in[9];
    float* out = (float*)d_out;

    int*   cnt_j   = (int*)d_ws;
    int*   cnt_k   = cnt_j + N_NODES;
    float* scale_j = (float*)(cnt_k + N_NODES);
    float* scale_k = scale_j + N_NODES;
    float* aggr    = scale_k + N_NODES;

    hipMemsetAsync(cnt_j, 0, (size_t)2 * N_NODES * sizeof(int), stream);
    hipMemsetAsync(aggr, 0, (size_t)N_NODES * 128 * sizeof(float), stream);

    count_kernel<<<(N_DIH + 255) / 256, 256, 0, stream>>>(qidx, cnt_j, cnt_k);
    scale_kernel<<<(N_NODES + 255) / 256, 256, 0, stream>>>(cnt_j, cnt_k, scale_j, scale_k);
    mlp_kernel<<<NBATCH, MB, 0, stream>>>(x, qidx, attr, W1, b1, W2, b2, W3, b3,
                                          scale_j, scale_k, aggr);
    out_kernel<<<(N_NODES + OTILE - 1) / OTILE, OB, 0, stream>>>(aggr, Wout, out);
}

// Round 3
// 1106.276 us; speedup vs baseline: 2.6732x; 1.8787x over previous
//
#include <hip/hip_runtime.h>

#define N_NODES    100000
#define N_DIH      1000000
#define SCALAR_DIM 128
#define HIDDEN     64
#define ATTR_DIM   3
#define D_IN       259

typedef short v8s __attribute__((ext_vector_type(8)));
typedef float v4f __attribute__((ext_vector_type(4)));

__device__ __forceinline__ float silu(float v) {
    return __fdividef(v, 1.0f + __expf(-v));
}

__device__ __forceinline__ unsigned short bf16_rne(float f) {
    unsigned int u = __float_as_uint(f);
    u = (u + 0x7FFFu + ((u >> 16) & 1u)) >> 16;
    return (unsigned short)u;
}

// ---------------- prep: x (fp32) -> xb (bf16) ----------------
__global__ void convert_x_kernel(const float* __restrict__ x, unsigned short* __restrict__ xb) {
    const int t = blockIdx.x * blockDim.x + threadIdx.x;   // 3.2M threads, 4 elems each
    const float4 v = *(const float4*)&x[(size_t)t * 4];
    ushort4 o;
    o.x = bf16_rne(v.x); o.y = bf16_rne(v.y); o.z = bf16_rne(v.z); o.w = bf16_rne(v.w);
    *(ushort4*)&xb[(size_t)t * 4] = o;
}

// ---------------- prep: swizzle W1/W2/W3 into MFMA B-frag order (bf16) ----------------
// B-frag element j for lane: B[k = kc*32 + (lane>>4)*8 + j][n = nt*16 + (lane&15)]
// flat layout: [(kc*NT + nt)*64 + lane]*8 + j
__global__ void convert_w_kernel(const float* __restrict__ W1, const float* __restrict__ W2,
                                 const float* __restrict__ W3,
                                 unsigned short* __restrict__ W1f,
                                 unsigned short* __restrict__ W2f,
                                 unsigned short* __restrict__ W3f) {
    const int tid = blockIdx.x * blockDim.x + threadIdx.x;   // 28672 total
    if (tid < 16384) {                     // W1f: kc<8, nt<4  (K=256 part only)
        const int j = tid & 7, lane = (tid >> 3) & 63, t = tid >> 9;   // t<32
        const int k = (t >> 2) * 32 + ((lane >> 4) << 3) + j;
        const int n = (t & 3) * 16 + (lane & 15);
        W1f[tid] = bf16_rne(W1[k * 64 + n]);
    } else if (tid < 20480) {              // W2f: kc<2, nt<4
        const int i = tid - 16384;
        const int j = i & 7, lane = (i >> 3) & 63, t = i >> 9;         // t<8
        const int k = (t >> 2) * 32 + ((lane >> 4) << 3) + j;
        const int n = (t & 3) * 16 + (lane & 15);
        W2f[i] = bf16_rne(W2[k * 64 + n]);
    } else if (tid < 28672) {              // W3f: kc<2, nt<8
        const int i = tid - 20480;
        const int j = i & 7, lane = (i >> 3) & 63, t = i >> 9;         // t<16
        const int k = (t >> 3) * 32 + ((lane >> 4) << 3) + j;
        const int n = (t & 7) * 16 + (lane & 15);
        W3f[i] = bf16_rne(W3[k * 128 + n]);
    }
}

__global__ void count_kernel(const int* __restrict__ qidx,
                             int* __restrict__ cnt_j, int* __restrict__ cnt_k) {
    int t = blockIdx.x * blockDim.x + threadIdx.x;
    if (t < N_DIH) {
        atomicAdd(&cnt_j[qidx[N_DIH + t]], 1);
        atomicAdd(&cnt_k[qidx[2 * N_DIH + t]], 1);
    }
}

__global__ void scale_kernel(const int* __restrict__ cnt_j, const int* __restrict__ cnt_k,
                             float* __restrict__ scale_j, float* __restrict__ scale_k) {
    int n = blockIdx.x * blockDim.x + threadIdx.x;
    if (n < N_NODES) {
        scale_j[n] = 0.5f / (float)max(cnt_j[n], 1);
        scale_k[n] = 0.5f / (float)max(cnt_k[n], 1);
    }
}

// ---------------- fused MLP, MFMA bf16, barrier-free wave-per-32-dihedrals ----------------
#define NWAVES 31250    // 1e6 / 32

__global__ __launch_bounds__(256, 3) void mlp_mfma(
    const unsigned short* __restrict__ xb, const int* __restrict__ qidx,
    const float* __restrict__ attr,
    const float* __restrict__ W1, const float* __restrict__ b1,
    const float* __restrict__ b2, const float* __restrict__ b3,
    const unsigned short* __restrict__ W1f, const unsigned short* __restrict__ W2f,
    const unsigned short* __restrict__ W3f,
    const float* __restrict__ scale_j, const float* __restrict__ scale_k,
    float* __restrict__ aggr)
{
    // per-wave private slab: h (2048 ushort) + h2 (2048 ushort), A-frag layout
    __shared__ unsigned short hbuf[4][4096];   // 32 KB/block

    const int tid  = threadIdx.x;
    const int lane = tid & 63;
    const int wv   = tid >> 6;
    const int g    = blockIdx.x * 4 + wv;
    if (g >= NWAVES) return;
    const int D0   = g * 32;
    const int m16  = lane & 15;
    const int quad = lane >> 4;
    unsigned short* hs = hbuf[wv];

    // gather row indices for A (i and l), per m-tile
    int irow[2], lrow[2];
    irow[0] = qidx[D0 + m16];
    irow[1] = qidx[D0 + 16 + m16];
    lrow[0] = qidx[3 * N_DIH + D0 + m16];
    lrow[1] = qidx[3 * N_DIH + D0 + 16 + m16];

    // ---------------- layer 1: K=256 via MFMA, attr (3 dims) + bias in fp32 epilogue ----
    v4f acc[2][4];
    #pragma unroll
    for (int mt = 0; mt < 2; ++mt)
        #pragma unroll
        for (int nt = 0; nt < 4; ++nt) acc[mt][nt] = (v4f){0.f, 0.f, 0.f, 0.f};

    #pragma unroll
    for (int kc = 0; kc < 8; ++kc) {
        const int side = kc >> 2;                       // 0: x_i, 1: x_l
        const int coff = (kc & 3) * 32 + quad * 8;      // col in [0,128)
        const int r0 = side ? lrow[0] : irow[0];
        const int r1 = side ? lrow[1] : irow[1];
        const v8s a0 = *(const v8s*)(xb + (size_t)r0 * 128 + coff);
        const v8s a1 = *(const v8s*)(xb + (size_t)r1 * 128 + coff);
        #pragma unroll
        for (int nt = 0; nt < 4; ++nt) {
            const v8s b = *(const v8s*)(W1f + ((kc * 4 + nt) * 64 + lane) * 8);
            acc[0][nt] = __builtin_amdgcn_mfma_f32_16x16x32_bf16(a0, b, acc[0][nt], 0, 0, 0);
            acc[1][nt] = __builtin_amdgcn_mfma_f32_16x16x32_bf16(a1, b, acc[1][nt], 0, 0, 0);
        }
    }

    // epilogue 1: + b1 + attr @ W1[256:259], silu, -> bf16 h in A-frag layout
    #pragma unroll
    for (int mt = 0; mt < 2; ++mt) {
        #pragma unroll
        for (int nt = 0; nt < 4; ++nt) {
            const int c = nt * 16 + m16;
            const float b1c = b1[c];
            const float wa0 = W1[256 * 64 + c];
            const float wa1 = W1[257 * 64 + c];
            const float wa2 = W1[258 * 64 + c];
            const int quadp = (nt * 2 + (m16 >> 3)) & 3;
            const int jp    = m16 & 7;
            const int kc2   = nt >> 1;
            #pragma unroll
            for (int reg = 0; reg < 4; ++reg) {
                const int r = quad * 4 + reg;
                const int d = D0 + mt * 16 + r;
                float v = acc[mt][nt][reg] + b1c
                        + attr[(size_t)d * 3 + 0] * wa0
                        + attr[(size_t)d * 3 + 1] * wa1
                        + attr[(size_t)d * 3 + 2] * wa2;
                v = silu(v);
                hs[mt * 1024 + kc2 * 512 + (r + 16 * quadp) * 8 + jp] = bf16_rne(v);
            }
        }
    }

    // ---------------- layer 2: 64 -> 64 ----------------
    v4f acc2[2][4];
    #pragma unroll
    for (int mt = 0; mt < 2; ++mt)
        #pragma unroll
        for (int nt = 0; nt < 4; ++nt) acc2[mt][nt] = (v4f){0.f, 0.f, 0.f, 0.f};

    #pragma unroll
    for (int kc = 0; kc < 2; ++kc) {
        const v8s a0 = *(const v8s*)(hs +        kc * 512 + lane * 8);
        const v8s a1 = *(const v8s*)(hs + 1024 + kc * 512 + lane * 8);
        #pragma unroll
        for (int nt = 0; nt < 4; ++nt) {
            const v8s b = *(const v8s*)(W2f + ((kc * 4 + nt) * 64 + lane) * 8);
            acc2[0][nt] = __builtin_amdgcn_mfma_f32_16x16x32_bf16(a0, b, acc2[0][nt], 0, 0, 0);
            acc2[1][nt] = __builtin_amdgcn_mfma_f32_16x16x32_bf16(a1, b, acc2[1][nt], 0, 0, 0);
        }
    }

    #pragma unroll
    for (int mt = 0; mt < 2; ++mt) {
        #pragma unroll
        for (int nt = 0; nt < 4; ++nt) {
            const int c = nt * 16 + m16;
            const float b2c = b2[c];
            const int quadp = (nt * 2 + (m16 >> 3)) & 3;
            const int jp    = m16 & 7;
            const int kc2   = nt >> 1;
            #pragma unroll
            for (int reg = 0; reg < 4; ++reg) {
                const int r = quad * 4 + reg;
                float v = silu(acc2[mt][nt][reg] + b2c);
                hs[2048 + mt * 1024 + kc2 * 512 + (r + 16 * quadp) * 8 + jp] = bf16_rne(v);
            }
        }
    }

    // ---------------- layer 3: 64 -> 128 ----------------
    v4f acc3[2][8];
    #pragma unroll
    for (int mt = 0; mt < 2; ++mt)
        #pragma unroll
        for (int nt = 0; nt < 8; ++nt) acc3[mt][nt] = (v4f){0.f, 0.f, 0.f, 0.f};

    #pragma unroll
    for (int kc = 0; kc < 2; ++kc) {
        const v8s a0 = *(const v8s*)(hs + 2048 +        kc * 512 + lane * 8);
        const v8s a1 = *(const v8s*)(hs + 2048 + 1024 + kc * 512 + lane * 8);
        #pragma unroll
        for (int nt = 0; nt < 8; ++nt) {
            const v8s b = *(const v8s*)(W3f + ((kc * 8 + nt) * 64 + lane) * 8);
            acc3[0][nt] = __builtin_amdgcn_mfma_f32_16x16x32_bf16(a0, b, acc3[0][nt], 0, 0, 0);
            acc3[1][nt] = __builtin_amdgcn_mfma_f32_16x16x32_bf16(a1, b, acc3[1][nt], 0, 0, 0);
        }
    }

    // epilogue 3: + b3, pre-scaled atomic scatter straight from C-frags
    #pragma unroll
    for (int mt = 0; mt < 2; ++mt) {
        int jn[4], kn[4]; float sjv[4], skv[4];
        #pragma unroll
        for (int reg = 0; reg < 4; ++reg) {
            const int d = D0 + mt * 16 + quad * 4 + reg;
            jn[reg] = qidx[N_DIH + d];
            kn[reg] = qidx[2 * N_DIH + d];
            sjv[reg] = scale_j[jn[reg]];
            skv[reg] = scale_k[kn[reg]];
        }
        #pragma unroll
        for (int nt = 0; nt < 8; ++nt) {
            const int c = nt * 16 + m16;
            const float b3c = b3[c];
            #pragma unroll
            for (int reg = 0; reg < 4; ++reg) {
                const float v = acc3[mt][nt][reg] + b3c;
                atomicAdd(&aggr[(size_t)jn[reg] * 128 + c], v * sjv[reg]);
                atomicAdd(&aggr[(size_t)kn[reg] * 128 + c], v * skv[reg]);
            }
        }
    }
}

// ---------------- out = aggr @ Wout (unchanged from R2) ----------------
#define OB    256
#define OTILE 64
__global__ __launch_bounds__(OB, 2) void out_kernel(const float* __restrict__ aggr,
                                                    const float* __restrict__ Wout,
                                                    float* __restrict__ out) {
    __shared__ float a_lds[OTILE * 132];
    const int tid  = threadIdx.x;
    const int lane = tid & 63;
    const int wv   = __builtin_amdgcn_readfirstlane(tid >> 6);
    const int base = blockIdx.x * OTILE;
    const int half = lane >> 5;
    const int q4   = (lane & 31) << 2;

    #pragma unroll
    for (int p = 0; p < 8; ++p) {
        const int ln = wv * 16 + p * 2 + half;
        const int n  = base + ln;
        float4 v = make_float4(0.f, 0.f, 0.f, 0.f);
        if (n < N_NODES) v = *(const float4*)&aggr[(size_t)n * 128 + q4];
        *(float4*)&a_lds[ln * 132 + q4] = v;
    }
    __syncthreads();

    const int c0 = wv * 32;
    float acc[32];
    #pragma unroll
    for (int c = 0; c < 32; ++c) acc[c] = 0.0f;
    const float* ap = &a_lds[lane * 132];
    #pragma unroll 2
    for (int d = 0; d < 128; d += 4) {
        const float4 av = *(const float4*)&ap[d];
        const float* w0 = &Wout[(d + 0) * 128 + c0];
        const float* w1 = &Wout[(d + 1) * 128 + c0];
        const float* w2 = &Wout[(d + 2) * 128 + c0];
        const float* w3 = &Wout[(d + 3) * 128 + c0];
        #pragma unroll
        for (int c = 0; c < 32; ++c)
            acc[c] += av.x * w0[c] + av.y * w1[c] + av.z * w2[c] + av.w * w3[c];
    }
    __syncthreads();
    #pragma unroll
    for (int c = 0; c < 32; c += 4)
        *(float4*)&a_lds[lane * 132 + c0 + c] = make_float4(acc[c], acc[c+1], acc[c+2], acc[c+3]);
    __syncthreads();
    #pragma unroll
    for (int p = 0; p < 8; ++p) {
        const int ln = wv * 16 + p * 2 + half;
        const int n  = base + ln;
        if (n < N_NODES)
            *(float4*)&out[(size_t)n * 128 + q4] = *(const float4*)&a_lds[ln * 132 + q4];
    }
}

extern "C" void kernel_launch(void* const* d_in, const int* in_sizes, int n_in,
                              void* d_out, int out_size, void* d_ws, size_t ws_size,
                              hipStream_t stream) {
    const float* x    = (const float*)d_in[0];
    const int*   qidx = (const int*)d_in[1];
    const float* attr = (const float*)d_in[2];
    const float* W1   = (const float*)d_in[3];
    const float* b1   = (const float*)d_in[4];
    const float* W2   = (const float*)d_in[5];
    const float* b2   = (const float*)d_in[6];
    const float* W3   = (const float*)d_in[7];
    const float* b3   = (const float*)d_in[8];
    const float* Wout = (const float*)d_in[9];
    float* out = (float*)d_out;

    // ws layout (float32 slots):
    // [0]       cnt_j  (int, 100k)
    // [100000]  cnt_k
    // [200000]  scale_j
    // [300000]  scale_k
    // [400000]  aggr   (12.8M f32)
    // [13200000] xb    (12.8M bf16 = 6.4M slots)
    // [19600000] W1f   (16384 bf16 = 8192 slots)
    // [19608192] W2f   (4096 bf16 = 2048 slots)
    // [19610240] W3f   (8192 bf16 = 4096 slots)   -> total 19,614,336 f32 = 78.5 MB
    float* wsf = (float*)d_ws;
    int*   cnt_j   = (int*)wsf;
    int*   cnt_k   = cnt_j + N_NODES;
    float* scale_j = wsf + 200000;
    float* scale_k = wsf + 300000;
    float* aggr    = wsf + 400000;
    unsigned short* xb  = (unsigned short*)(wsf + 13200000);
    unsigned short* W1f = (unsigned short*)(wsf + 19600000);
    unsigned short* W2f = (unsigned short*)(wsf + 19608192);
    unsigned short* W3f = (unsigned short*)(wsf + 19610240);

    hipMemsetAsync(cnt_j, 0, (size_t)2 * N_NODES * sizeof(int), stream);
    hipMemsetAsync(aggr, 0, (size_t)N_NODES * 128 * sizeof(float), stream);

    convert_x_kernel<<<12500, 256, 0, stream>>>(x, xb);
    convert_w_kernel<<<112, 256, 0, stream>>>(W1, W2, W3, W1f, W2f, W3f);
    count_kernel<<<(N_DIH + 255) / 256, 256, 0, stream>>>(qidx, cnt_j, cnt_k);
    scale_kernel<<<(N_NODES + 255) / 256, 256, 0, stream>>>(cnt_j, cnt_k, scale_j, scale_k);
    mlp_mfma<<<(NWAVES + 3) / 4, 256, 0, stream>>>(xb, qidx, attr, W1, b1, b2, b3,
                                                   W1f, W2f, W3f, scale_j, scale_k, aggr);
    out_kernel<<<(N_NODES + OTILE - 1) / OTILE, OB, 0, stream>>>(aggr, Wout, out);
}

// Round 5
// 1070.656 us; speedup vs baseline: 2.7621x; 1.0333x over previous
//
#include <hip/hip_runtime.h>

#define N_NODES    100000
#define N_DIH      1000000
#define SCALAR_DIM 128
#define HIDDEN     64
#define ATTR_DIM   3

typedef short v8s __attribute__((ext_vector_type(8)));
typedef float v4f __attribute__((ext_vector_type(4)));

__device__ __forceinline__ float silu(float v) {
    return __fdividef(v, 1.0f + __expf(-v));
}

__device__ __forceinline__ unsigned short bf16_rne(float f) {
    unsigned int u = __float_as_uint(f);
    u = (u + 0x7FFFu + ((u >> 16) & 1u)) >> 16;
    return (unsigned short)u;
}

__device__ __forceinline__ float bf_to_f(unsigned short u) {
    return __uint_as_float(((unsigned int)u) << 16);
}

// ---------------- prep: x->bf16, W->frags, histogram (fused) ----------------
#define PREP_XB 12500
#define PREP_W  112
#define PREP_H  3907

__global__ void prep_kernel(const float* __restrict__ x, unsigned short* __restrict__ xb,
                            const float* __restrict__ W1, const float* __restrict__ W2,
                            const float* __restrict__ W3,
                            unsigned short* __restrict__ W1f, unsigned short* __restrict__ W2f,
                            unsigned short* __restrict__ W3f,
                            const int* __restrict__ qidx,
                            int* __restrict__ cnt_j, int* __restrict__ cnt_k) {
    const int b = blockIdx.x;
    if (b < PREP_XB) {
        const int t = b * 256 + threadIdx.x;
        const float4 v = *(const float4*)&x[(size_t)t * 4];
        ushort4 o;
        o.x = bf16_rne(v.x); o.y = bf16_rne(v.y); o.z = bf16_rne(v.z); o.w = bf16_rne(v.w);
        *(ushort4*)&xb[(size_t)t * 4] = o;
    } else if (b < PREP_XB + PREP_W) {
        const int tid = (b - PREP_XB) * 256 + threadIdx.x;
        if (tid < 16384) {                     // W1f: kc<8, nt<4
            const int j = tid & 7, lane = (tid >> 3) & 63, t = tid >> 9;
            const int k = (t >> 2) * 32 + ((lane >> 4) << 3) + j;
            const int n = (t & 3) * 16 + (lane & 15);
            W1f[tid] = bf16_rne(W1[k * 64 + n]);
        } else if (tid < 20480) {              // W2f: kc<2, nt<4
            const int i = tid - 16384;
            const int j = i & 7, lane = (i >> 3) & 63, t = i >> 9;
            const int k = (t >> 2) * 32 + ((lane >> 4) << 3) + j;
            const int n = (t & 3) * 16 + (lane & 15);
            W2f[i] = bf16_rne(W2[k * 64 + n]);
        } else if (tid < 28672) {              // W3f: kc<2, nt<8
            const int i = tid - 20480;
            const int j = i & 7, lane = (i >> 3) & 63, t = i >> 9;
            const int k = (t >> 3) * 32 + ((lane >> 4) << 3) + j;
            const int n = (t & 7) * 16 + (lane & 15);
            W3f[i] = bf16_rne(W3[k * 128 + n]);
        }
    } else {
        const int t = (b - PREP_XB - PREP_W) * 256 + threadIdx.x;
        if (t < N_DIH) {
            atomicAdd(&cnt_j[qidx[N_DIH + t]], 1);
            atomicAdd(&cnt_k[qidx[2 * N_DIH + t]], 1);
        }
    }
}

// ---------------- scan: exclusive prefix over counts -> off + cur ----------------
__global__ __launch_bounds__(1024) void scan_kernel(const int* __restrict__ cnt_j,
                                                    const int* __restrict__ cnt_k,
                                                    int* __restrict__ off_j, int* __restrict__ off_k,
                                                    int* __restrict__ cur_j, int* __restrict__ cur_k) {
    const int* cnt = blockIdx.x ? cnt_k : cnt_j;
    int* off = blockIdx.x ? off_k : off_j;
    int* cur = blockIdx.x ? cur_k : cur_j;
    __shared__ int wtot[17];
    const int tid = threadIdx.x, lane = tid & 63, wv = tid >> 6;
    int carry = 0;
    for (int base = 0; base < N_NODES; base += 1024) {
        const int i = base + tid;
        const int v = (i < N_NODES) ? cnt[i] : 0;
        int inc = v;
        #pragma unroll
        for (int o = 1; o < 64; o <<= 1) {
            const int t = __shfl_up(inc, o);
            if (lane >= o) inc += t;
        }
        if (lane == 63) wtot[wv] = inc;
        __syncthreads();
        if (tid == 0) {
            int run = 0;
            #pragma unroll
            for (int w = 0; w < 16; ++w) { const int t = wtot[w]; wtot[w] = run; run += t; }
            wtot[16] = run;
        }
        __syncthreads();
        const int excl = inc - v + wtot[wv] + carry;
        if (i < N_NODES) { off[i] = excl; cur[i] = excl; }
        carry += wtot[16];
        __syncthreads();
    }
    if (tid == 0) off[N_NODES] = carry;
}

// ---------------- permute: counting-sort edge ids ----------------
__global__ void permute_kernel(const int* __restrict__ qidx,
                               int* __restrict__ cur_j, int* __restrict__ cur_k,
                               int* __restrict__ perm_j, int* __restrict__ perm_k) {
    const int t = blockIdx.x * blockDim.x + threadIdx.x;
    if (t < N_DIH) {
        const int j = qidx[N_DIH + t];
        perm_j[atomicAdd(&cur_j[j], 1)] = t;
        const int k = qidx[2 * N_DIH + t];
        perm_k[atomicAdd(&cur_k[k], 1)] = t;
    }
}

// ================= CSR path: MLP computing channels [c0, c0+C) =================
#define NWAVES 31250    // 1e6 / 32

template<int C>
__global__ __launch_bounds__(256, 3) void mlp_mfma_csr(
    const unsigned short* __restrict__ xb, const int* __restrict__ qidx,
    const float* __restrict__ attr,
    const float* __restrict__ W1, const float* __restrict__ b1,
    const float* __restrict__ b2, const float* __restrict__ b3,
    const unsigned short* __restrict__ W1f, const unsigned short* __restrict__ W2f,
    const unsigned short* __restrict__ W3f,
    unsigned short* __restrict__ msgs, const int c0)
{
    constexpr int NT3 = C / 16;
    __shared__ __align__(16) unsigned short hbuf[4][4096];

    const int tid  = threadIdx.x;
    const int lane = tid & 63;
    const int wv   = tid >> 6;
    const int g    = blockIdx.x * 4 + wv;
    if (g >= NWAVES) return;
    const int D0   = g * 32;
    const int m16  = lane & 15;
    const int quad = lane >> 4;
    unsigned short* hs = hbuf[wv];

    int irow[2], lrow[2];
    irow[0] = qidx[D0 + m16];
    irow[1] = qidx[D0 + 16 + m16];
    lrow[0] = qidx[3 * N_DIH + D0 + m16];
    lrow[1] = qidx[3 * N_DIH + D0 + 16 + m16];

    // ---- layer 1: K=256 via MFMA ----
    v4f acc[2][4];
    #pragma unroll
    for (int mt = 0; mt < 2; ++mt)
        #pragma unroll
        for (int nt = 0; nt < 4; ++nt) acc[mt][nt] = (v4f){0.f, 0.f, 0.f, 0.f};

    #pragma unroll
    for (int kc = 0; kc < 8; ++kc) {
        const int side = kc >> 2;
        const int coff = (kc & 3) * 32 + quad * 8;
        const int r0 = side ? lrow[0] : irow[0];
        const int r1 = side ? lrow[1] : irow[1];
        const v8s a0 = *(const v8s*)(xb + (size_t)r0 * 128 + coff);
        const v8s a1 = *(const v8s*)(xb + (size_t)r1 * 128 + coff);
        #pragma unroll
        for (int nt = 0; nt < 4; ++nt) {
            const v8s b = *(const v8s*)(W1f + ((kc * 4 + nt) * 64 + lane) * 8);
            acc[0][nt] = __builtin_amdgcn_mfma_f32_16x16x32_bf16(a0, b, acc[0][nt], 0, 0, 0);
            acc[1][nt] = __builtin_amdgcn_mfma_f32_16x16x32_bf16(a1, b, acc[1][nt], 0, 0, 0);
        }
    }

    // epilogue 1: + b1 + attr @ W1[256:259], silu -> bf16 h (A-frag layout)
    #pragma unroll
    for (int mt = 0; mt < 2; ++mt) {
        #pragma unroll
        for (int nt = 0; nt < 4; ++nt) {
            const int c = nt * 16 + m16;
            const float b1c = b1[c];
            const float wa0 = W1[256 * 64 + c];
            const float wa1 = W1[257 * 64 + c];
            const float wa2 = W1[258 * 64 + c];
            const int quadp = (nt * 2 + (m16 >> 3)) & 3;
            const int jp    = m16 & 7;
            const int kc2   = nt >> 1;
            #pragma unroll
            for (int reg = 0; reg < 4; ++reg) {
                const int r = quad * 4 + reg;
                const int d = D0 + mt * 16 + r;
                float v = acc[mt][nt][reg] + b1c
                        + attr[(size_t)d * 3 + 0] * wa0
                        + attr[(size_t)d * 3 + 1] * wa1
                        + attr[(size_t)d * 3 + 2] * wa2;
                v = silu(v);
                hs[mt * 1024 + kc2 * 512 + (r + 16 * quadp) * 8 + jp] = bf16_rne(v);
            }
        }
    }

    // ---- layer 2: 64 -> 64 ----
    v4f acc2[2][4];
    #pragma unroll
    for (int mt = 0; mt < 2; ++mt)
        #pragma unroll
        for (int nt = 0; nt < 4; ++nt) acc2[mt][nt] = (v4f){0.f, 0.f, 0.f, 0.f};

    #pragma unroll
    for (int kc = 0; kc < 2; ++kc) {
        const v8s a0 = *(const v8s*)(hs +        kc * 512 + lane * 8);
        const v8s a1 = *(const v8s*)(hs + 1024 + kc * 512 + lane * 8);
        #pragma unroll
        for (int nt = 0; nt < 4; ++nt) {
            const v8s b = *(const v8s*)(W2f + ((kc * 4 + nt) * 64 + lane) * 8);
            acc2[0][nt] = __builtin_amdgcn_mfma_f32_16x16x32_bf16(a0, b, acc2[0][nt], 0, 0, 0);
            acc2[1][nt] = __builtin_amdgcn_mfma_f32_16x16x32_bf16(a1, b, acc2[1][nt], 0, 0, 0);
        }
    }

    #pragma unroll
    for (int mt = 0; mt < 2; ++mt) {
        #pragma unroll
        for (int nt = 0; nt < 4; ++nt) {
            const float b2c = b2[nt * 16 + m16];
            const int quadp = (nt * 2 + (m16 >> 3)) & 3;
            const int jp    = m16 & 7;
            const int kc2   = nt >> 1;
            #pragma unroll
            for (int reg = 0; reg < 4; ++reg) {
                const int r = quad * 4 + reg;
                const float v = silu(acc2[mt][nt][reg] + b2c);
                hs[2048 + mt * 1024 + kc2 * 512 + (r + 16 * quadp) * 8 + jp] = bf16_rne(v);
            }
        }
    }

    // ---- layer 3: 64 -> C (channels [c0, c0+C)) ----
    v4f acc3[2][NT3];
    #pragma unroll
    for (int mt = 0; mt < 2; ++mt)
        #pragma unroll
        for (int nt = 0; nt < NT3; ++nt) acc3[mt][nt] = (v4f){0.f, 0.f, 0.f, 0.f};

    const int ntbase = c0 >> 4;
    #pragma unroll
    for (int kc = 0; kc < 2; ++kc) {
        const v8s a0 = *(const v8s*)(hs + 2048 +        kc * 512 + lane * 8);
        const v8s a1 = *(const v8s*)(hs + 2048 + 1024 + kc * 512 + lane * 8);
        #pragma unroll
        for (int nt = 0; nt < NT3; ++nt) {
            const v8s b = *(const v8s*)(W3f + ((kc * 8 + ntbase + nt) * 64 + lane) * 8);
            acc3[0][nt] = __builtin_amdgcn_mfma_f32_16x16x32_bf16(a0, b, acc3[0][nt], 0, 0, 0);
            acc3[1][nt] = __builtin_amdgcn_mfma_f32_16x16x32_bf16(a1, b, acc3[1][nt], 0, 0, 0);
        }
    }

    // epilogue 3: + b3 -> bf16 rows (chunk-local) in LDS, then coalesced store
    #pragma unroll
    for (int mt = 0; mt < 2; ++mt) {
        #pragma unroll
        for (int nt = 0; nt < NT3; ++nt) {
            const int cl = nt * 16 + m16;
            const float b3c = b3[c0 + cl];
            #pragma unroll
            for (int reg = 0; reg < 4; ++reg) {
                const int row = mt * 16 + quad * 4 + reg;
                hs[row * C + cl] = bf16_rne(acc3[mt][nt][reg] + b3c);
            }
        }
    }
    #pragma unroll
    for (int i = 0; i < C / 16; ++i) {
        const v8s row16 = *(const v8s*)(hs + i * 512 + lane * 8);
        *(v8s*)(msgs + (size_t)D0 * C + i * 512 + lane * 8) = row16;
    }
}

// ====== CSR aggregate (gather-mean) + partial Wout GEMM over K=[c0,c0+C) ======
template<int C>
__global__ __launch_bounds__(256, 2) void aggregate_out_csr(
    const unsigned short* __restrict__ msgs,
    const int* __restrict__ off_j, const int* __restrict__ off_k,
    const int* __restrict__ perm_j, const int* __restrict__ perm_k,
    const float* __restrict__ Wout, float* __restrict__ out,
    const int c0, const int accum)
{
    __shared__ float a_lds[64 * 132];
    const int tid  = threadIdx.x;
    const int lane = tid & 63;
    const int wv   = __builtin_amdgcn_readfirstlane(tid >> 6);  // 0..3
    const int base = blockIdx.x * 64;

    // phase 1: wave wv does nodes [base+wv*16, +16); lane = chunk channel
    for (int p = 0; p < 16; ++p) {
        const int ln = wv * 16 + p;
        const int n  = base + ln;
        float s = 0.f;
        if (n < N_NODES && lane < C) {
            {   // j-list
                const int e0 = off_j[n], e1 = off_j[n + 1];
                float a = 0.f; int e = e0;
                for (; e + 4 <= e1; e += 4) {
                    const int d0 = perm_j[e], d1 = perm_j[e+1], d2 = perm_j[e+2], d3 = perm_j[e+3];
                    const float f0 = bf_to_f(msgs[(size_t)d0 * C + lane]);
                    const float f1 = bf_to_f(msgs[(size_t)d1 * C + lane]);
                    const float f2 = bf_to_f(msgs[(size_t)d2 * C + lane]);
                    const float f3 = bf_to_f(msgs[(size_t)d3 * C + lane]);
                    a += (f0 + f1) + (f2 + f3);
                }
                for (; e < e1; ++e) a += bf_to_f(msgs[(size_t)perm_j[e] * C + lane]);
                s += a * (1.0f / (float)max(e1 - e0, 1));
            }
            {   // k-list
                const int e0 = off_k[n], e1 = off_k[n + 1];
                float a = 0.f; int e = e0;
                for (; e + 4 <= e1; e += 4) {
                    const int d0 = perm_k[e], d1 = perm_k[e+1], d2 = perm_k[e+2], d3 = perm_k[e+3];
                    const float f0 = bf_to_f(msgs[(size_t)d0 * C + lane]);
                    const float f1 = bf_to_f(msgs[(size_t)d1 * C + lane]);
                    const float f2 = bf_to_f(msgs[(size_t)d2 * C + lane]);
                    const float f3 = bf_to_f(msgs[(size_t)d3 * C + lane]);
                    a += (f0 + f1) + (f2 + f3);
                }
                for (; e < e1; ++e) a += bf_to_f(msgs[(size_t)perm_k[e] * C + lane]);
                s += a * (1.0f / (float)max(e1 - e0, 1));
            }
        }
        if (lane < C) a_lds[ln * 132 + lane] = s * 0.5f;
    }
    __syncthreads();

    // phase 2: out[base..][0..127] (+)= a_lds[.., 0..C) @ Wout[c0..c0+C)
    const int co = wv * 32;
    float acc[32];
    #pragma unroll
    for (int c = 0; c < 32; ++c) acc[c] = 0.0f;
    const float* ap = &a_lds[lane * 132];
    #pragma unroll 2
    for (int d = 0; d < C; d += 4) {
        const float4 av = *(const float4*)&ap[d];
        const float* w0 = &Wout[(size_t)(c0 + d) * 128 + co];
        const float* w1 = w0 + 128;
        const float* w2 = w0 + 256;
        const float* w3 = w0 + 384;
        #pragma unroll
        for (int c = 0; c < 32; ++c)
            acc[c] += av.x * w0[c] + av.y * w1[c] + av.z * w2[c] + av.w * w3[c];
    }
    __syncthreads();
    #pragma unroll
    for (int c = 0; c < 32; c += 4)
        *(float4*)&a_lds[lane * 132 + co + c] = make_float4(acc[c], acc[c+1], acc[c+2], acc[c+3]);
    __syncthreads();
    const int half = lane >> 5;
    const int q4   = (lane & 31) << 2;
    #pragma unroll
    for (int p = 0; p < 8; ++p) {
        const int ln = wv * 16 + p * 2 + half;
        const int n  = base + ln;
        if (n < N_NODES) {
            float4 v = *(const float4*)&a_lds[ln * 132 + q4];
            if (accum) {
                const float4 cu = *(const float4*)&out[(size_t)n * 128 + q4];
                v.x += cu.x; v.y += cu.y; v.z += cu.z; v.w += cu.w;
            }
            *(float4*)&out[(size_t)n * 128 + q4] = v;
        }
    }
}

// ================= fallback (proven R3 atomic path) =================
__global__ void scale_kernel(const int* __restrict__ cnt_j, const int* __restrict__ cnt_k,
                             float* __restrict__ scale_j, float* __restrict__ scale_k) {
    int n = blockIdx.x * blockDim.x + threadIdx.x;
    if (n < N_NODES) {
        scale_j[n] = 0.5f / (float)max(cnt_j[n], 1);
        scale_k[n] = 0.5f / (float)max(cnt_k[n], 1);
    }
}

__global__ __launch_bounds__(256, 3) void mlp_mfma_atomic(
    const unsigned short* __restrict__ xb, const int* __restrict__ qidx,
    const float* __restrict__ attr,
    const float* __restrict__ W1, const float* __restrict__ b1,
    const float* __restrict__ b2, const float* __restrict__ b3,
    const unsigned short* __restrict__ W1f, const unsigned short* __restrict__ W2f,
    const unsigned short* __restrict__ W3f,
    const float* __restrict__ scale_j, const float* __restrict__ scale_k,
    float* __restrict__ aggr)
{
    __shared__ __align__(16) unsigned short hbuf[4][4096];
    const int tid  = threadIdx.x;
    const int lane = tid & 63;
    const int wv   = tid >> 6;
    const int g    = blockIdx.x * 4 + wv;
    if (g >= NWAVES) return;
    const int D0   = g * 32;
    const int m16  = lane & 15;
    const int quad = lane >> 4;
    unsigned short* hs = hbuf[wv];

    int irow[2], lrow[2];
    irow[0] = qidx[D0 + m16];
    irow[1] = qidx[D0 + 16 + m16];
    lrow[0] = qidx[3 * N_DIH + D0 + m16];
    lrow[1] = qidx[3 * N_DIH + D0 + 16 + m16];

    v4f acc[2][4];
    #pragma unroll
    for (int mt = 0; mt < 2; ++mt)
        #pragma unroll
        for (int nt = 0; nt < 4; ++nt) acc[mt][nt] = (v4f){0.f, 0.f, 0.f, 0.f};
    #pragma unroll
    for (int kc = 0; kc < 8; ++kc) {
        const int side = kc >> 2;
        const int coff = (kc & 3) * 32 + quad * 8;
        const int r0 = side ? lrow[0] : irow[0];
        const int r1 = side ? lrow[1] : irow[1];
        const v8s a0 = *(const v8s*)(xb + (size_t)r0 * 128 + coff);
        const v8s a1 = *(const v8s*)(xb + (size_t)r1 * 128 + coff);
        #pragma unroll
        for (int nt = 0; nt < 4; ++nt) {
            const v8s b = *(const v8s*)(W1f + ((kc * 4 + nt) * 64 + lane) * 8);
            acc[0][nt] = __builtin_amdgcn_mfma_f32_16x16x32_bf16(a0, b, acc[0][nt], 0, 0, 0);
            acc[1][nt] = __builtin_amdgcn_mfma_f32_16x16x32_bf16(a1, b, acc[1][nt], 0, 0, 0);
        }
    }
    #pragma unroll
    for (int mt = 0; mt < 2; ++mt) {
        #pragma unroll
        for (int nt = 0; nt < 4; ++nt) {
            const int c = nt * 16 + m16;
            const float b1c = b1[c];
            const float wa0 = W1[256 * 64 + c];
            const float wa1 = W1[257 * 64 + c];
            const float wa2 = W1[258 * 64 + c];
            const int quadp = (nt * 2 + (m16 >> 3)) & 3;
            const int jp    = m16 & 7;
            const int kc2   = nt >> 1;
            #pragma unroll
            for (int reg = 0; reg < 4; ++reg) {
                const int r = quad * 4 + reg;
                const int d = D0 + mt * 16 + r;
                float v = acc[mt][nt][reg] + b1c
                        + attr[(size_t)d * 3 + 0] * wa0
                        + attr[(size_t)d * 3 + 1] * wa1
                        + attr[(size_t)d * 3 + 2] * wa2;
                v = silu(v);
                hs[mt * 1024 + kc2 * 512 + (r + 16 * quadp) * 8 + jp] = bf16_rne(v);
            }
        }
    }
    v4f acc2[2][4];
    #pragma unroll
    for (int mt = 0; mt < 2; ++mt)
        #pragma unroll
        for (int nt = 0; nt < 4; ++nt) acc2[mt][nt] = (v4f){0.f, 0.f, 0.f, 0.f};
    #pragma unroll
    for (int kc = 0; kc < 2; ++kc) {
        const v8s a0 = *(const v8s*)(hs +        kc * 512 + lane * 8);
        const v8s a1 = *(const v8s*)(hs + 1024 + kc * 512 + lane * 8);
        #pragma unroll
        for (int nt = 0; nt < 4; ++nt) {
            const v8s b = *(const v8s*)(W2f + ((kc * 4 + nt) * 64 + lane) * 8);
            acc2[0][nt] = __builtin_amdgcn_mfma_f32_16x16x32_bf16(a0, b, acc2[0][nt], 0, 0, 0);
            acc2[1][nt] = __builtin_amdgcn_mfma_f32_16x16x32_bf16(a1, b, acc2[1][nt], 0, 0, 0);
        }
    }
    #pragma unroll
    for (int mt = 0; mt < 2; ++mt) {
        #pragma unroll
        for (int nt = 0; nt < 4; ++nt) {
            const float b2c = b2[nt * 16 + m16];
            const int quadp = (nt * 2 + (m16 >> 3)) & 3;
            const int jp    = m16 & 7;
            const int kc2   = nt >> 1;
            #pragma unroll
            for (int reg = 0; reg < 4; ++reg) {
                const int r = quad * 4 + reg;
                const float v = silu(acc2[mt][nt][reg] + b2c);
                hs[2048 + mt * 1024 + kc2 * 512 + (r + 16 * quadp) * 8 + jp] = bf16_rne(v);
            }
        }
    }
    v4f acc3[2][8];
    #pragma unroll
    for (int mt = 0; mt < 2; ++mt)
        #pragma unroll
        for (int nt = 0; nt < 8; ++nt) acc3[mt][nt] = (v4f){0.f, 0.f, 0.f, 0.f};
    #pragma unroll
    for (int kc = 0; kc < 2; ++kc) {
        const v8s a0 = *(const v8s*)(hs + 2048 +        kc * 512 + lane * 8);
        const v8s a1 = *(const v8s*)(hs + 2048 + 1024 + kc * 512 + lane * 8);
        #pragma unroll
        for (int nt = 0; nt < 8; ++nt) {
            const v8s b = *(const v8s*)(W3f + ((kc * 8 + nt) * 64 + lane) * 8);
            acc3[0][nt] = __builtin_amdgcn_mfma_f32_16x16x32_bf16(a0, b, acc3[0][nt], 0, 0, 0);
            acc3[1][nt] = __builtin_amdgcn_mfma_f32_16x16x32_bf16(a1, b, acc3[1][nt], 0, 0, 0);
        }
    }
    #pragma unroll
    for (int mt = 0; mt < 2; ++mt) {
        int jn[4], kn[4]; float sjv[4], skv[4];
        #pragma unroll
        for (int reg = 0; reg < 4; ++reg) {
            const int d = D0 + mt * 16 + quad * 4 + reg;
            jn[reg] = qidx[N_DIH + d];
            kn[reg] = qidx[2 * N_DIH + d];
            sjv[reg] = scale_j[jn[reg]];
            skv[reg] = scale_k[kn[reg]];
        }
        #pragma unroll
        for (int nt = 0; nt < 8; ++nt) {
            const int c = nt * 16 + m16;
            const float b3c = b3[c];
            #pragma unroll
            for (int reg = 0; reg < 4; ++reg) {
                const float v = acc3[mt][nt][reg] + b3c;
                atomicAdd(&aggr[(size_t)jn[reg] * 128 + c], v * sjv[reg]);
                atomicAdd(&aggr[(size_t)kn[reg] * 128 + c], v * skv[reg]);
            }
        }
    }
}

#define OB    256
#define OTILE 64
__global__ __launch_bounds__(OB, 2) void out_kernel(const float* __restrict__ aggr,
                                                    const float* __restrict__ Wout,
                                                    float* __restrict__ out) {
    __shared__ float a_lds[OTILE * 132];
    const int tid  = threadIdx.x;
    const int lane = tid & 63;
    const int wv   = __builtin_amdgcn_readfirstlane(tid >> 6);
    const int base = blockIdx.x * OTILE;
    const int half = lane >> 5;
    const int q4   = (lane & 31) << 2;
    #pragma unroll
    for (int p = 0; p < 8; ++p) {
        const int ln = wv * 16 + p * 2 + half;
        const int n  = base + ln;
        float4 v = make_float4(0.f, 0.f, 0.f, 0.f);
        if (n < N_NODES) v = *(const float4*)&aggr[(size_t)n * 128 + q4];
        *(float4*)&a_lds[ln * 132 + q4] = v;
    }
    __syncthreads();
    const int c0 = wv * 32;
    float acc[32];
    #pragma unroll
    for (int c = 0; c < 32; ++c) acc[c] = 0.0f;
    const float* ap = &a_lds[lane * 132];
    #pragma unroll 2
    for (int d = 0; d < 128; d += 4) {
        const float4 av = *(const float4*)&ap[d];
        const float* w0 = &Wout[(d + 0) * 128 + c0];
        const float* w1 = &Wout[(d + 1) * 128 + c0];
        const float* w2 = &Wout[(d + 2) * 128 + c0];
        const float* w3 = &Wout[(d + 3) * 128 + c0];
        #pragma unroll
        for (int c = 0; c < 32; ++c)
            acc[c] += av.x * w0[c] + av.y * w1[c] + av.z * w2[c] + av.w * w3[c];
    }
    __syncthreads();
    #pragma unroll
    for (int c = 0; c < 32; c += 4)
        *(float4*)&a_lds[lane * 132 + c0 + c] = make_float4(acc[c], acc[c+1], acc[c+2], acc[c+3]);
    __syncthreads();
    #pragma unroll
    for (int p = 0; p < 8; ++p) {
        const int ln = wv * 16 + p * 2 + half;
        const int n  = base + ln;
        if (n < N_NODES)
            *(float4*)&out[(size_t)n * 128 + q4] = *(const float4*)&a_lds[ln * 132 + q4];
    }
}

extern "C" void kernel_launch(void* const* d_in, const int* in_sizes, int n_in,
                              void* d_out, int out_size, void* d_ws, size_t ws_size,
                              hipStream_t stream) {
    const float* x    = (const float*)d_in[0];
    const int*   qidx = (const int*)d_in[1];
    const float* attr = (const float*)d_in[2];
    const float* W1   = (const float*)d_in[3];
    const float* b1   = (const float*)d_in[4];
    const float* W2   = (const float*)d_in[5];
    const float* b2   = (const float*)d_in[6];
    const float* W3   = (const float*)d_in[7];
    const float* b3   = (const float*)d_in[8];
    const float* Wout = (const float*)d_in[9];
    float* out = (float*)d_out;
    float* wsf = (float*)d_ws;

    const size_t words = ws_size / 4;
    // CSR tier requirements (words): msgs(500000*C) + fixed 9,014,338
    const int C = (words >= (size_t)32000000 + 9014338) ? 64
                : (words >= (size_t)16000000 + 9014338) ? 32 : 0;

    if (C > 0) {
        // ---- CSR path ----
        const size_t msgs_words = (size_t)500000 * C;
        unsigned short* msgs = (unsigned short*)wsf;
        size_t o = msgs_words;
        unsigned short* xb  = (unsigned short*)(wsf + o); o += 6400000;
        unsigned short* W1f = (unsigned short*)(wsf + o); o += 8192;
        unsigned short* W2f = (unsigned short*)(wsf + o); o += 2048;
        unsigned short* W3f = (unsigned short*)(wsf + o); o += 4096;
        int* cnt_j  = (int*)(wsf + o); o += 100000;
        int* cnt_k  = (int*)(wsf + o); o += 100000;
        int* off_j  = (int*)(wsf + o); o += 100001;
        int* off_k  = (int*)(wsf + o); o += 100001;
        int* cur_j  = (int*)(wsf + o); o += 100000;
        int* cur_k  = (int*)(wsf + o); o += 100000;
        int* perm_j = (int*)(wsf + o); o += 1000000;
        int* perm_k = (int*)(wsf + o); o += 1000000;

        hipMemsetAsync(cnt_j, 0, (size_t)200000 * sizeof(int), stream);
        prep_kernel<<<PREP_XB + PREP_W + PREP_H, 256, 0, stream>>>(
            x, xb, W1, W2, W3, W1f, W2f, W3f, qidx, cnt_j, cnt_k);
        scan_kernel<<<2, 1024, 0, stream>>>(cnt_j, cnt_k, off_j, off_k, cur_j, cur_k);
        permute_kernel<<<(N_DIH + 255) / 256, 256, 0, stream>>>(qidx, cur_j, cur_k, perm_j, perm_k);

        const int npass = 128 / C;
        for (int p = 0; p < npass; ++p) {
            const int c0 = p * C;
            if (C == 64) {
                mlp_mfma_csr<64><<<(NWAVES + 3) / 4, 256, 0, stream>>>(
                    xb, qidx, attr, W1, b1, b2, b3, W1f, W2f, W3f, msgs, c0);
                aggregate_out_csr<64><<<(N_NODES + 63) / 64, 256, 0, stream>>>(
                    msgs, off_j, off_k, perm_j, perm_k, Wout, out, c0, p);
            } else {
                mlp_mfma_csr<32><<<(NWAVES + 3) / 4, 256, 0, stream>>>(
                    xb, qidx, attr, W1, b1, b2, b3, W1f, W2f, W3f, msgs, c0);
                aggregate_out_csr<32><<<(N_NODES + 63) / 64, 256, 0, stream>>>(
                    msgs, off_j, off_k, perm_j, perm_k, Wout, out, c0, p);
            }
        }
    } else {
        // ---- fallback: proven R3 atomic path (78.5 MB) ----
        int*   cnt_j   = (int*)wsf;
        int*   cnt_k   = cnt_j + N_NODES;
        float* scale_j = wsf + 200000;
        float* scale_k = wsf + 300000;
        float* aggr    = wsf + 400000;
        unsigned short* xb  = (unsigned short*)(wsf + 13200000);
        unsigned short* W1f = (unsigned short*)(wsf + 19600000);
        unsigned short* W2f = (unsigned short*)(wsf + 19608192);
        unsigned short* W3f = (unsigned short*)(wsf + 19610240);

        hipMemsetAsync(cnt_j, 0, (size_t)2 * N_NODES * sizeof(int), stream);
        hipMemsetAsync(aggr, 0, (size_t)N_NODES * 128 * sizeof(float), stream);
        prep_kernel<<<PREP_XB + PREP_W + PREP_H, 256, 0, stream>>>(
            x, xb, W1, W2, W3, W1f, W2f, W3f, qidx, cnt_j, cnt_k);
        scale_kernel<<<(N_NODES + 255) / 256, 256, 0, stream>>>(cnt_j, cnt_k, scale_j, scale_k);
        mlp_mfma_atomic<<<(NWAVES + 3) / 4, 256, 0, stream>>>(
            xb, qidx, attr, W1, b1, b2, b3, W1f, W2f, W3f, scale_j, scale_k, aggr);
        out_kernel<<<(N_NODES + OTILE - 1) / OTILE, OB, 0, stream>>>(aggr, Wout, out);
    }
}

// Round 6
// 824.556 us; speedup vs baseline: 3.5865x; 1.2985x over previous
//
#include <hip/hip_runtime.h>

#define N_NODES    100000
#define N_DIH      1000000
#define SCALAR_DIM 128
#define HIDDEN     64
#define ATTR_DIM   3

typedef short v8s __attribute__((ext_vector_type(8)));
typedef float v4f __attribute__((ext_vector_type(4)));

__device__ __forceinline__ float silu(float v) {
    return __fdividef(v, 1.0f + __expf(-v));
}

__device__ __forceinline__ unsigned short bf16_rne(float f) {
    unsigned int u = __float_as_uint(f);
    u = (u + 0x7FFFu + ((u >> 16) & 1u)) >> 16;
    return (unsigned short)u;
}

__device__ __forceinline__ float2 bf2_to_f2(unsigned int v) {
    float2 r;
    r.x = __uint_as_float(v << 16);
    r.y = __uint_as_float(v & 0xffff0000u);
    return r;
}

// ---------------- prep: x->bf16, W->frags, W34=W3@Wout, b34=b3@Wout, histogram ----
#define PREP_XB  12500
#define PREP_W   112
#define PREP_W34 33
#define PREP_H   3907

__global__ void prep_kernel(const float* __restrict__ x, unsigned short* __restrict__ xb,
                            const float* __restrict__ W1, const float* __restrict__ W2,
                            const float* __restrict__ W3, const float* __restrict__ b3,
                            const float* __restrict__ Wout,
                            unsigned short* __restrict__ W1f, unsigned short* __restrict__ W2f,
                            unsigned short* __restrict__ W3f,
                            float* __restrict__ W34, float* __restrict__ b34,
                            const int* __restrict__ qidx,
                            int* __restrict__ cnt_j, int* __restrict__ cnt_k) {
    const int b = blockIdx.x;
    if (b < PREP_XB) {
        const int t = b * 256 + threadIdx.x;
        const float4 v = *(const float4*)&x[(size_t)t * 4];
        ushort4 o;
        o.x = bf16_rne(v.x); o.y = bf16_rne(v.y); o.z = bf16_rne(v.z); o.w = bf16_rne(v.w);
        *(ushort4*)&xb[(size_t)t * 4] = o;
    } else if (b < PREP_XB + PREP_W) {
        const int tid = (b - PREP_XB) * 256 + threadIdx.x;
        if (tid < 16384) {                     // W1f: kc<8, nt<4
            const int j = tid & 7, lane = (tid >> 3) & 63, t = tid >> 9;
            const int k = (t >> 2) * 32 + ((lane >> 4) << 3) + j;
            const int n = (t & 3) * 16 + (lane & 15);
            W1f[tid] = bf16_rne(W1[k * 64 + n]);
        } else if (tid < 20480) {              // W2f: kc<2, nt<4
            const int i = tid - 16384;
            const int j = i & 7, lane = (i >> 3) & 63, t = i >> 9;
            const int k = (t >> 2) * 32 + ((lane >> 4) << 3) + j;
            const int n = (t & 3) * 16 + (lane & 15);
            W2f[i] = bf16_rne(W2[k * 64 + n]);
        } else if (tid < 28672) {              // W3f (fallback path only)
            const int i = tid - 20480;
            const int j = i & 7, lane = (i >> 3) & 63, t = i >> 9;
            const int k = (t >> 3) * 32 + ((lane >> 4) << 3) + j;
            const int n = (t & 7) * 16 + (lane & 15);
            W3f[i] = bf16_rne(W3[k * 128 + n]);
        }
    } else if (b < PREP_XB + PREP_W + PREP_W34) {
        const int t34 = (b - PREP_XB - PREP_W) * 256 + threadIdx.x;
        if (t34 < 8192) {                      // W34[r][c] = sum_m W3[r][m]*Wout[m][c]
            const int r = t34 >> 7, c = t34 & 127;
            float s = 0.f;
            #pragma unroll 4
            for (int m = 0; m < 128; ++m) s += W3[r * 128 + m] * Wout[m * 128 + c];
            W34[t34] = s;
        } else if (t34 < 8320) {               // b34[c] = sum_m b3[m]*Wout[m][c]
            const int c = t34 - 8192;
            float s = 0.f;
            #pragma unroll 4
            for (int m = 0; m < 128; ++m) s += b3[m] * Wout[m * 128 + c];
            b34[c] = s;
        }
    } else {
        const int t = (b - PREP_XB - PREP_W - PREP_W34) * 256 + threadIdx.x;
        if (t < N_DIH) {
            atomicAdd(&cnt_j[qidx[N_DIH + t]], 1);
            atomicAdd(&cnt_k[qidx[2 * N_DIH + t]], 1);
        }
    }
}

// ---------------- scan: exclusive prefix over counts -> off + cur ----------------
__global__ __launch_bounds__(1024) void scan_kernel(const int* __restrict__ cnt_j,
                                                    const int* __restrict__ cnt_k,
                                                    int* __restrict__ off_j, int* __restrict__ off_k,
                                                    int* __restrict__ cur_j, int* __restrict__ cur_k) {
    const int* cnt = blockIdx.x ? cnt_k : cnt_j;
    int* off = blockIdx.x ? off_k : off_j;
    int* cur = blockIdx.x ? cur_k : cur_j;
    __shared__ int wtot[17];
    const int tid = threadIdx.x, lane = tid & 63, wv = tid >> 6;
    int carry = 0;
    for (int base = 0; base < N_NODES; base += 1024) {
        const int i = base + tid;
        const int v = (i < N_NODES) ? cnt[i] : 0;
        int inc = v;
        #pragma unroll
        for (int o = 1; o < 64; o <<= 1) {
            const int t = __shfl_up(inc, o);
            if (lane >= o) inc += t;
        }
        if (lane == 63) wtot[wv] = inc;
        __syncthreads();
        if (tid == 0) {
            int run = 0;
            #pragma unroll
            for (int w = 0; w < 16; ++w) { const int t = wtot[w]; wtot[w] = run; run += t; }
            wtot[16] = run;
        }
        __syncthreads();
        const int excl = inc - v + wtot[wv] + carry;
        if (i < N_NODES) { off[i] = excl; cur[i] = excl; }
        carry += wtot[16];
        __syncthreads();
    }
    if (tid == 0) off[N_NODES] = carry;
}

// ---------------- permute: counting-sort edge ids ----------------
__global__ void permute_kernel(const int* __restrict__ qidx,
                               int* __restrict__ cur_j, int* __restrict__ cur_k,
                               int* __restrict__ perm_j, int* __restrict__ perm_k) {
    const int t = blockIdx.x * blockDim.x + threadIdx.x;
    if (t < N_DIH) {
        const int j = qidx[N_DIH + t];
        perm_j[atomicAdd(&cur_j[j], 1)] = t;
        const int k = qidx[2 * N_DIH + t];
        perm_k[atomicAdd(&cur_k[k], 1)] = t;
    }
}

// ========== MLP layers 1+2 only -> h2 (bf16, row-major 1M x 64) ==========
#define NWAVES 31250    // 1e6 / 32

__global__ __launch_bounds__(256, 3) void mlp12_kernel(
    const unsigned short* __restrict__ xb, const int* __restrict__ qidx,
    const float* __restrict__ attr,
    const float* __restrict__ W1, const float* __restrict__ b1,
    const float* __restrict__ b2,
    const unsigned short* __restrict__ W1f, const unsigned short* __restrict__ W2f,
    unsigned short* __restrict__ h2)
{
    __shared__ __align__(16) unsigned short hbuf[4][4096];   // per wave: [0,2048)=h1 A-frag, [2048,4096)=h2 rows

    const int tid  = threadIdx.x;
    const int lane = tid & 63;
    const int wv   = tid >> 6;
    const int g    = blockIdx.x * 4 + wv;
    if (g >= NWAVES) return;
    const int D0   = g * 32;
    const int m16  = lane & 15;
    const int quad = lane >> 4;
    unsigned short* hs = hbuf[wv];

    int irow[2], lrow[2];
    irow[0] = qidx[D0 + m16];
    irow[1] = qidx[D0 + 16 + m16];
    lrow[0] = qidx[3 * N_DIH + D0 + m16];
    lrow[1] = qidx[3 * N_DIH + D0 + 16 + m16];

    // ---- layer 1: K=256 via MFMA ----
    v4f acc[2][4];
    #pragma unroll
    for (int mt = 0; mt < 2; ++mt)
        #pragma unroll
        for (int nt = 0; nt < 4; ++nt) acc[mt][nt] = (v4f){0.f, 0.f, 0.f, 0.f};

    #pragma unroll
    for (int kc = 0; kc < 8; ++kc) {
        const int side = kc >> 2;
        const int coff = (kc & 3) * 32 + quad * 8;
        const int r0 = side ? lrow[0] : irow[0];
        const int r1 = side ? lrow[1] : irow[1];
        const v8s a0 = *(const v8s*)(xb + (size_t)r0 * 128 + coff);
        const v8s a1 = *(const v8s*)(xb + (size_t)r1 * 128 + coff);
        #pragma unroll
        for (int nt = 0; nt < 4; ++nt) {
            const v8s b = *(const v8s*)(W1f + ((kc * 4 + nt) * 64 + lane) * 8);
            acc[0][nt] = __builtin_amdgcn_mfma_f32_16x16x32_bf16(a0, b, acc[0][nt], 0, 0, 0);
            acc[1][nt] = __builtin_amdgcn_mfma_f32_16x16x32_bf16(a1, b, acc[1][nt], 0, 0, 0);
        }
    }

    // epilogue 1: + b1 + attr @ W1[256:259], silu -> bf16 h1 (A-frag layout)
    #pragma unroll
    for (int mt = 0; mt < 2; ++mt) {
        #pragma unroll
        for (int nt = 0; nt < 4; ++nt) {
            const int c = nt * 16 + m16;
            const float b1c = b1[c];
            const float wa0 = W1[256 * 64 + c];
            const float wa1 = W1[257 * 64 + c];
            const float wa2 = W1[258 * 64 + c];
            const int quadp = (nt * 2 + (m16 >> 3)) & 3;
            const int jp    = m16 & 7;
            const int kc2   = nt >> 1;
            #pragma unroll
            for (int reg = 0; reg < 4; ++reg) {
                const int r = quad * 4 + reg;
                const int d = D0 + mt * 16 + r;
                float v = acc[mt][nt][reg] + b1c
                        + attr[(size_t)d * 3 + 0] * wa0
                        + attr[(size_t)d * 3 + 1] * wa1
                        + attr[(size_t)d * 3 + 2] * wa2;
                v = silu(v);
                hs[mt * 1024 + kc2 * 512 + (r + 16 * quadp) * 8 + jp] = bf16_rne(v);
            }
        }
    }

    // ---- layer 2: 64 -> 64 ----
    v4f acc2[2][4];
    #pragma unroll
    for (int mt = 0; mt < 2; ++mt)
        #pragma unroll
        for (int nt = 0; nt < 4; ++nt) acc2[mt][nt] = (v4f){0.f, 0.f, 0.f, 0.f};

    #pragma unroll
    for (int kc = 0; kc < 2; ++kc) {
        const v8s a0 = *(const v8s*)(hs +        kc * 512 + lane * 8);
        const v8s a1 = *(const v8s*)(hs + 1024 + kc * 512 + lane * 8);
        #pragma unroll
        for (int nt = 0; nt < 4; ++nt) {
            const v8s b = *(const v8s*)(W2f + ((kc * 4 + nt) * 64 + lane) * 8);
            acc2[0][nt] = __builtin_amdgcn_mfma_f32_16x16x32_bf16(a0, b, acc2[0][nt], 0, 0, 0);
            acc2[1][nt] = __builtin_amdgcn_mfma_f32_16x16x32_bf16(a1, b, acc2[1][nt], 0, 0, 0);
        }
    }

    // epilogue 2: silu -> bf16 rows [row][c], then coalesced global store
    #pragma unroll
    for (int mt = 0; mt < 2; ++mt) {
        #pragma unroll
        for (int nt = 0; nt < 4; ++nt) {
            const int c = nt * 16 + m16;
            const float b2c = b2[c];
            #pragma unroll
            for (int reg = 0; reg < 4; ++reg) {
                const int row = mt * 16 + quad * 4 + reg;
                hs[2048 + row * 64 + c] = bf16_rne(silu(acc2[mt][nt][reg] + b2c));
            }
        }
    }
    #pragma unroll
    for (int i = 0; i < 4; ++i) {
        const v8s row16 = *(const v8s*)(hs + 2048 + i * 512 + lane * 8);
        *(v8s*)(h2 + (size_t)D0 * 64 + i * 512 + lane * 8) = row16;
    }
}

// ====== aggregate h2 (gather-mean, paired-row) + fused W34 GEMM + b34 bias ======
__global__ __launch_bounds__(256, 2) void aggregate_out64(
    const unsigned short* __restrict__ h2,
    const int* __restrict__ off_j, const int* __restrict__ off_k,
    const int* __restrict__ perm_j, const int* __restrict__ perm_k,
    const float* __restrict__ W34, const float* __restrict__ b34,
    float* __restrict__ out)
{
    __shared__ float a_lds[64 * 132];   // [node][0..63]=aggH, [128]=bias flag
    const int tid    = threadIdx.x;
    const int lane   = tid & 63;
    const int wv     = __builtin_amdgcn_readfirstlane(tid >> 6);  // 0..3
    const int base   = blockIdx.x * 64;
    const int half   = lane >> 5;
    const int lane31 = lane & 31;

    // phase 1: wave wv aggregates nodes [base+wv*16, +16); lane-halves pair rows
    for (int p = 0; p < 16; ++p) {
        const int ln = wv * 16 + p;
        const int n  = base + ln;
        float sx = 0.f, sy = 0.f, bf = 0.f;
        if (n < N_NODES) {
            int cj, ck;
            {   // j-list
                const int e0 = off_j[n], e1 = off_j[n + 1];
                cj = e1 - e0;
                float ax = 0.f, ay = 0.f;
                int e = e0;
                for (; e + 4 <= e1; e += 4) {
                    const int dA = perm_j[e + half];
                    const int dB = perm_j[e + 2 + half];
                    const float2 fA = bf2_to_f2(*(const unsigned int*)(h2 + (size_t)dA * 64 + lane31 * 2));
                    const float2 fB = bf2_to_f2(*(const unsigned int*)(h2 + (size_t)dB * 64 + lane31 * 2));
                    ax += fA.x + fB.x; ay += fA.y + fB.y;
                }
                if (e + 2 <= e1) {
                    const int d = perm_j[e + half];
                    const float2 f = bf2_to_f2(*(const unsigned int*)(h2 + (size_t)d * 64 + lane31 * 2));
                    ax += f.x; ay += f.y;
                    e += 2;
                }
                if (e < e1 && half == 0) {
                    const int d = perm_j[e];
                    const float2 f = bf2_to_f2(*(const unsigned int*)(h2 + (size_t)d * 64 + lane31 * 2));
                    ax += f.x; ay += f.y;
                }
                ax += __shfl_xor(ax, 32);
                ay += __shfl_xor(ay, 32);
                const float inv = 1.0f / (float)max(cj, 1);
                sx += ax * inv; sy += ay * inv;
            }
            {   // k-list
                const int e0 = off_k[n], e1 = off_k[n + 1];
                ck = e1 - e0;
                float ax = 0.f, ay = 0.f;
                int e = e0;
                for (; e + 4 <= e1; e += 4) {
                    const int dA = perm_k[e + half];
                    const int dB = perm_k[e + 2 + half];
                    const float2 fA = bf2_to_f2(*(const unsigned int*)(h2 + (size_t)dA * 64 + lane31 * 2));
                    const float2 fB = bf2_to_f2(*(const unsigned int*)(h2 + (size_t)dB * 64 + lane31 * 2));
                    ax += fA.x + fB.x; ay += fA.y + fB.y;
                }
                if (e + 2 <= e1) {
                    const int d = perm_k[e + half];
                    const float2 f = bf2_to_f2(*(const unsigned int*)(h2 + (size_t)d * 64 + lane31 * 2));
                    ax += f.x; ay += f.y;
                    e += 2;
                }
                if (e < e1 && half == 0) {
                    const int d = perm_k[e];
                    const float2 f = bf2_to_f2(*(const unsigned int*)(h2 + (size_t)d * 64 + lane31 * 2));
                    ax += f.x; ay += f.y;
                }
                ax += __shfl_xor(ax, 32);
                ay += __shfl_xor(ay, 32);
                const float inv = 1.0f / (float)max(ck, 1);
                sx += ax * inv; sy += ay * inv;
            }
            bf = 0.5f * ((float)(cj > 0) + (float)(ck > 0));
        }
        if (half == 0) {
            float2 w; w.x = sx * 0.5f; w.y = sy * 0.5f;
            *(float2*)&a_lds[ln * 132 + 2 * lane31] = w;
            if (lane31 == 0) a_lds[ln * 132 + 128] = bf;
        }
    }
    __syncthreads();

    // phase 2: out[n] = aggH[n] @ W34 + bf*b34  (lane = node, W34 via scalar loads)
    const int co = wv * 32;
    const float bfv = a_lds[lane * 132 + 128];
    float acc[32];
    #pragma unroll
    for (int c = 0; c < 32; ++c) acc[c] = bfv * b34[co + c];
    const float* ap = &a_lds[lane * 132];
    #pragma unroll 2
    for (int d = 0; d < 64; d += 4) {
        const float4 av = *(const float4*)&ap[d];
        const float* w0 = &W34[(d + 0) * 128 + co];
        const float* w1 = w0 + 128;
        const float* w2 = w0 + 256;
        const float* w3 = w0 + 384;
        #pragma unroll
        for (int c = 0; c < 32; ++c)
            acc[c] += av.x * w0[c] + av.y * w1[c] + av.z * w2[c] + av.w * w3[c];
    }
    __syncthreads();
    #pragma unroll
    for (int c = 0; c < 32; c += 4)
        *(float4*)&a_lds[lane * 132 + co + c] = make_float4(acc[c], acc[c+1], acc[c+2], acc[c+3]);
    __syncthreads();
    const int q4 = lane31 << 2;
    #pragma unroll
    for (int p = 0; p < 8; ++p) {
        const int ln = wv * 16 + p * 2 + half;
        const int n  = base + ln;
        if (n < N_NODES)
            *(float4*)&out[(size_t)n * 128 + q4] = *(const float4*)&a_lds[ln * 132 + q4];
    }
}

// ================= fallback (proven R3 atomic path) =================
__global__ void scale_kernel(const int* __restrict__ cnt_j, const int* __restrict__ cnt_k,
                             float* __restrict__ scale_j, float* __restrict__ scale_k) {
    int n = blockIdx.x * blockDim.x + threadIdx.x;
    if (n < N_NODES) {
        scale_j[n] = 0.5f / (float)max(cnt_j[n], 1);
        scale_k[n] = 0.5f / (float)max(cnt_k[n], 1);
    }
}

__global__ __launch_bounds__(256, 3) void mlp_mfma_atomic(
    const unsigned short* __restrict__ xb, const int* __restrict__ qidx,
    const float* __restrict__ attr,
    const float* __restrict__ W1, const float* __restrict__ b1,
    const float* __restrict__ b2, const float* __restrict__ b3,
    const unsigned short* __restrict__ W1f, const unsigned short* __restrict__ W2f,
    const unsigned short* __restrict__ W3f,
    const float* __restrict__ scale_j, const float* __restrict__ scale_k,
    float* __restrict__ aggr)
{
    __shared__ __align__(16) unsigned short hbuf[4][4096];
    const int tid  = threadIdx.x;
    const int lane = tid & 63;
    const int wv   = tid >> 6;
    const int g    = blockIdx.x * 4 + wv;
    if (g >= NWAVES) return;
    const int D0   = g * 32;
    const int m16  = lane & 15;
    const int quad = lane >> 4;
    unsigned short* hs = hbuf[wv];

    int irow[2], lrow[2];
    irow[0] = qidx[D0 + m16];
    irow[1] = qidx[D0 + 16 + m16];
    lrow[0] = qidx[3 * N_DIH + D0 + m16];
    lrow[1] = qidx[3 * N_DIH + D0 + 16 + m16];

    v4f acc[2][4];
    #pragma unroll
    for (int mt = 0; mt < 2; ++mt)
        #pragma unroll
        for (int nt = 0; nt < 4; ++nt) acc[mt][nt] = (v4f){0.f, 0.f, 0.f, 0.f};
    #pragma unroll
    for (int kc = 0; kc < 8; ++kc) {
        const int side = kc >> 2;
        const int coff = (kc & 3) * 32 + quad * 8;
        const int r0 = side ? lrow[0] : irow[0];
        const int r1 = side ? lrow[1] : irow[1];
        const v8s a0 = *(const v8s*)(xb + (size_t)r0 * 128 + coff);
        const v8s a1 = *(const v8s*)(xb + (size_t)r1 * 128 + coff);
        #pragma unroll
        for (int nt = 0; nt < 4; ++nt) {
            const v8s b = *(const v8s*)(W1f + ((kc * 4 + nt) * 64 + lane) * 8);
            acc[0][nt] = __builtin_amdgcn_mfma_f32_16x16x32_bf16(a0, b, acc[0][nt], 0, 0, 0);
            acc[1][nt] = __builtin_amdgcn_mfma_f32_16x16x32_bf16(a1, b, acc[1][nt], 0, 0, 0);
        }
    }
    #pragma unroll
    for (int mt = 0; mt < 2; ++mt) {
        #pragma unroll
        for (int nt = 0; nt < 4; ++nt) {
            const int c = nt * 16 + m16;
            const float b1c = b1[c];
            const float wa0 = W1[256 * 64 + c];
            const float wa1 = W1[257 * 64 + c];
            const float wa2 = W1[258 * 64 + c];
            const int quadp = (nt * 2 + (m16 >> 3)) & 3;
            const int jp    = m16 & 7;
            const int kc2   = nt >> 1;
            #pragma unroll
            for (int reg = 0; reg < 4; ++reg) {
                const int r = quad * 4 + reg;
                const int d = D0 + mt * 16 + r;
                float v = acc[mt][nt][reg] + b1c
                        + attr[(size_t)d * 3 + 0] * wa0
                        + attr[(size_t)d * 3 + 1] * wa1
                        + attr[(size_t)d * 3 + 2] * wa2;
                v = silu(v);
                hs[mt * 1024 + kc2 * 512 + (r + 16 * quadp) * 8 + jp] = bf16_rne(v);
            }
        }
    }
    v4f acc2[2][4];
    #pragma unroll
    for (int mt = 0; mt < 2; ++mt)
        #pragma unroll
        for (int nt = 0; nt < 4; ++nt) acc2[mt][nt] = (v4f){0.f, 0.f, 0.f, 0.f};
    #pragma unroll
    for (int kc = 0; kc < 2; ++kc) {
        const v8s a0 = *(const v8s*)(hs +        kc * 512 + lane * 8);
        const v8s a1 = *(const v8s*)(hs + 1024 + kc * 512 + lane * 8);
        #pragma unroll
        for (int nt = 0; nt < 4; ++nt) {
            const v8s b = *(const v8s*)(W2f + ((kc * 4 + nt) * 64 + lane) * 8);
            acc2[0][nt] = __builtin_amdgcn_mfma_f32_16x16x32_bf16(a0, b, acc2[0][nt], 0, 0, 0);
            acc2[1][nt] = __builtin_amdgcn_mfma_f32_16x16x32_bf16(a1, b, acc2[1][nt], 0, 0, 0);
        }
    }
    #pragma unroll
    for (int mt = 0; mt < 2; ++mt) {
        #pragma unroll
        for (int nt = 0; nt < 4; ++nt) {
            const float b2c = b2[nt * 16 + m16];
            const int quadp = (nt * 2 + (m16 >> 3)) & 3;
            const int jp    = m16 & 7;
            const int kc2   = nt >> 1;
            #pragma unroll
            for (int reg = 0; reg < 4; ++reg) {
                const int r = quad * 4 + reg;
                const float v = silu(acc2[mt][nt][reg] + b2c);
                hs[2048 + mt * 1024 + kc2 * 512 + (r + 16 * quadp) * 8 + jp] = bf16_rne(v);
            }
        }
    }
    v4f acc3[2][8];
    #pragma unroll
    for (int mt = 0; mt < 2; ++mt)
        #pragma unroll
        for (int nt = 0; nt < 8; ++nt) acc3[mt][nt] = (v4f){0.f, 0.f, 0.f, 0.f};
    #pragma unroll
    for (int kc = 0; kc < 2; ++kc) {
        const v8s a0 = *(const v8s*)(hs + 2048 +        kc * 512 + lane * 8);
        const v8s a1 = *(const v8s*)(hs + 2048 + 1024 + kc * 512 + lane * 8);
        #pragma unroll
        for (int nt = 0; nt < 8; ++nt) {
            const v8s b = *(const v8s*)(W3f + ((kc * 8 + nt) * 64 + lane) * 8);
            acc3[0][nt] = __builtin_amdgcn_mfma_f32_16x16x32_bf16(a0, b, acc3[0][nt], 0, 0, 0);
            acc3[1][nt] = __builtin_amdgcn_mfma_f32_16x16x32_bf16(a1, b, acc3[1][nt], 0, 0, 0);
        }
    }
    #pragma unroll
    for (int mt = 0; mt < 2; ++mt) {
        int jn[4], kn[4]; float sjv[4], skv[4];
        #pragma unroll
        for (int reg = 0; reg < 4; ++reg) {
            const int d = D0 + mt * 16 + quad * 4 + reg;
            jn[reg] = qidx[N_DIH + d];
            kn[reg] = qidx[2 * N_DIH + d];
            sjv[reg] = scale_j[jn[reg]];
            skv[reg] = scale_k[kn[reg]];
        }
        #pragma unroll
        for (int nt = 0; nt < 8; ++nt) {
            const int c = nt * 16 + m16;
            const float b3c = b3[c];
            #pragma unroll
            for (int reg = 0; reg < 4; ++reg) {
                const float v = acc3[mt][nt][reg] + b3c;
                atomicAdd(&aggr[(size_t)jn[reg] * 128 + c], v * sjv[reg]);
                atomicAdd(&aggr[(size_t)kn[reg] * 128 + c], v * skv[reg]);
            }
        }
    }
}

#define OB    256
#define OTILE 64
__global__ __launch_bounds__(OB, 2) void out_kernel(const float* __restrict__ aggr,
                                                    const float* __restrict__ Wout,
                                                    float* __restrict__ out) {
    __shared__ float a_lds[OTILE * 132];
    const int tid  = threadIdx.x;
    const int lane = tid & 63;
    const int wv   = __builtin_amdgcn_readfirstlane(tid >> 6);
    const int base = blockIdx.x * OTILE;
    const int half = lane >> 5;
    const int q4   = (lane & 31) << 2;
    #pragma unroll
    for (int p = 0; p < 8; ++p) {
        const int ln = wv * 16 + p * 2 + half;
        const int n  = base + ln;
        float4 v = make_float4(0.f, 0.f, 0.f, 0.f);
        if (n < N_NODES) v = *(const float4*)&aggr[(size_t)n * 128 + q4];
        *(float4*)&a_lds[ln * 132 + q4] = v;
    }
    __syncthreads();
    const int c0 = wv * 32;
    float acc[32];
    #pragma unroll
    for (int c = 0; c < 32; ++c) acc[c] = 0.0f;
    const float* ap = &a_lds[lane * 132];
    #pragma unroll 2
    for (int d = 0; d < 128; d += 4) {
        const float4 av = *(const float4*)&ap[d];
        const float* w0 = &Wout[(d + 0) * 128 + c0];
        const float* w1 = &Wout[(d + 1) * 128 + c0];
        const float* w2 = &Wout[(d + 2) * 128 + c0];
        const float* w3 = &Wout[(d + 3) * 128 + c0];
        #pragma unroll
        for (int c = 0; c < 32; ++c)
            acc[c] += av.x * w0[c] + av.y * w1[c] + av.z * w2[c] + av.w * w3[c];
    }
    __syncthreads();
    #pragma unroll
    for (int c = 0; c < 32; c += 4)
        *(float4*)&a_lds[lane * 132 + c0 + c] = make_float4(acc[c], acc[c+1], acc[c+2], acc[c+3]);
    __syncthreads();
    #pragma unroll
    for (int p = 0; p < 8; ++p) {
        const int ln = wv * 16 + p * 2 + half;
        const int n  = base + ln;
        if (n < N_NODES)
            *(float4*)&out[(size_t)n * 128 + q4] = *(const float4*)&a_lds[ln * 132 + q4];
    }
}

extern "C" void kernel_launch(void* const* d_in, const int* in_sizes, int n_in,
                              void* d_out, int out_size, void* d_ws, size_t ws_size,
                              hipStream_t stream) {
    const float* x    = (const float*)d_in[0];
    const int*   qidx = (const int*)d_in[1];
    const float* attr = (const float*)d_in[2];
    const float* W1   = (const float*)d_in[3];
    const float* b1   = (const float*)d_in[4];
    const float* W2   = (const float*)d_in[5];
    const float* b2   = (const float*)d_in[6];
    const float* W3   = (const float*)d_in[7];
    const float* b3   = (const float*)d_in[8];
    const float* Wout = (const float*)d_in[9];
    float* out = (float*)d_out;
    float* wsf = (float*)d_ws;

    const size_t words = ws_size / 4;
    // main path needs 41,022,658 words (164.1 MB); require a little headroom
    if (words >= (size_t)41100000) {
        size_t o = 0;
        unsigned short* h2  = (unsigned short*)wsf;          o += 32000000;
        unsigned short* xb  = (unsigned short*)(wsf + o);    o += 6400000;
        unsigned short* W1f = (unsigned short*)(wsf + o);    o += 8192;
        unsigned short* W2f = (unsigned short*)(wsf + o);    o += 2048;
        unsigned short* W3f = (unsigned short*)(wsf + o);    o += 4096;
        float* W34  = wsf + o;                               o += 8192;
        float* b34  = wsf + o;                               o += 128;
        int* cnt_j  = (int*)(wsf + o);                       o += 100000;
        int* cnt_k  = (int*)(wsf + o);                       o += 100000;
        int* off_j  = (int*)(wsf + o);                       o += 100001;
        int* off_k  = (int*)(wsf + o);                       o += 100001;
        int* cur_j  = (int*)(wsf + o);                       o += 100000;
        int* cur_k  = (int*)(wsf + o);                       o += 100000;
        int* perm_j = (int*)(wsf + o);                       o += 1000000;
        int* perm_k = (int*)(wsf + o);                       o += 1000000;

        hipMemsetAsync(cnt_j, 0, (size_t)200000 * sizeof(int), stream);
        prep_kernel<<<PREP_XB + PREP_W + PREP_W34 + PREP_H, 256, 0, stream>>>(
            x, xb, W1, W2, W3, b3, Wout, W1f, W2f, W3f, W34, b34, qidx, cnt_j, cnt_k);
        scan_kernel<<<2, 1024, 0, stream>>>(cnt_j, cnt_k, off_j, off_k, cur_j, cur_k);
        permute_kernel<<<(N_DIH + 255) / 256, 256, 0, stream>>>(qidx, cur_j, cur_k, perm_j, perm_k);
        mlp12_kernel<<<(NWAVES + 3) / 4, 256, 0, stream>>>(
            xb, qidx, attr, W1, b1, b2, W1f, W2f, h2);
        aggregate_out64<<<(N_NODES + 63) / 64, 256, 0, stream>>>(
            h2, off_j, off_k, perm_j, perm_k, W34, b34, out);
    } else {
        // ---- fallback: proven R3 atomic path (78.5 MB) ----
        int*   cnt_j   = (int*)wsf;
        int*   cnt_k   = cnt_j + N_NODES;
        float* scale_j = wsf + 200000;
        float* scale_k = wsf + 300000;
        float* aggr    = wsf + 400000;
        unsigned short* xb  = (unsigned short*)(wsf + 13200000);
        unsigned short* W1f = (unsigned short*)(wsf + 19600000);
        unsigned short* W2f = (unsigned short*)(wsf + 19608192);
        unsigned short* W3f = (unsigned short*)(wsf + 19610240);
        float* W34 = wsf + 19612288;   // scratch (unused result ok)
        float* b34 = wsf + 19612288;   // overlap fine for fallback

        hipMemsetAsync(cnt_j, 0, (size_t)2 * N_NODES * sizeof(int), stream);
        hipMemsetAsync(aggr, 0, (size_t)N_NODES * 128 * sizeof(float), stream);
        prep_kernel<<<PREP_XB + PREP_W + PREP_W34 + PREP_H, 256, 0, stream>>>(
            x, xb, W1, W2, W3, b3, Wout, W1f, W2f, W3f, W34, b34, qidx, cnt_j, cnt_k);
        scale_kernel<<<(N_NODES + 255) / 256, 256, 0, stream>>>(cnt_j, cnt_k, scale_j, scale_k);
        mlp_mfma_atomic<<<(NWAVES + 3) / 4, 256, 0, stream>>>(
            xb, qidx, attr, W1, b1, b2, b3, W1f, W2f, W3f, scale_j, scale_k, aggr);
        out_kernel<<<(N_NODES + OTILE - 1) / OTILE, OB, 0, stream>>>(aggr, Wout, out);
    }
}